// Round 8
// baseline (1601.079 us; speedup 1.0000x reference)
//
#include <hip/hip_runtime.h>
#include <math.h>

// ---------------- problem constants ----------------
#define BATCH 2
#define NTOK 256
#define INCH 384
#define NP 50176          // 224*224
#define HW 224
#define NPROTO 64
#define EMBD 32

// ---------------- workspace layout (floats) ----------------
#define OFF_FEATS0   0u
#define OFF_FEATS1   131072u
#define OFF_FEATS2   393216u
#define OFF_FEATS3   917504u
#define OFF_TOKT     1441792u
#define OFF_F0       2228224u
#define OFF_F1       4325376u
#define OFF_F3       5373952u
#define OFF_FUSEDBF  5505024u      // (2,4096,2816) bf16 = 11.53M fl -> ends 17.04M
#define OFF_WD       5505024u      // down-conv packed weights (9.44M fl) — dead-FUSEDBF window
#define OFF_PART     14942208u     // down-conv K-split partials (2.10M fl) -> ends 17039360
#define OFF_P64C     28573696u     // (2,4096,256) bf16 channels-last
#define OFF_P224C    0u            // (2,224,224,256) bf16 = 12.85M fl
#define OFF_T1       25690112u     // (2,128,224,224) fp32
#define OFF_PC2      0u            // conv2 K-split partials (4x2x32xNP = 12.85M fl, dead-P224C window)
#define OFF_PSM      25690112u     // smooth K-split partials (2x2x64xNP = 12.85M fl, dead-T1 window)
#define OFF_SIMA     0u
#define OFF_SIMB     6422528u
#define OFF_EDGE     12845056u
#define OFF_RES      13000000u
#define OFF_WB       13000000u     // conv1 MFMA weight frags (dead-RES window, written after fuse)
#define OFF_SHIFT    13200000u
#define OFF_BGAIN    19422528u
#define OFF_BB       19522880u
#define OFF_ACC      19523008u
#define OFF_WF       19523072u     // folded head weights (42496 fl)
#define OFF_WFUSE    20000000u     // fuse MFMA weight frags: 720896 bf16 = 360448 fl
#define OFF_WCV0     20500000u     // convT F0 packed W: 1048576 fl
#define OFF_WCV1     21600000u     // convT F1 packed W: 1048576 fl -> ends 22.65M
#define OFF_WC2      22700000u     // conv2 packed W [c][tap][o]: 36864 fl
#define OFF_WSM      22750000u     // smooth packed W [c][tap][o]: 36864 fl -> ends 22.79M (< T1 @25.69M)

// ---------------- output layout ----------------
#define O_IBM 0u
#define O_ACT 100352u
#define O_BB  6522880u
#define O_WT  6523008u
#define O_PE  6623360u
#define O_ENT 9834624u

typedef __attribute__((ext_vector_type(8))) short bf16x8;
typedef __attribute__((ext_vector_type(4))) float f32x4;
typedef __attribute__((ext_vector_type(2))) float f32x2;

__device__ __forceinline__ short f2bf(float f) {
    unsigned u = __float_as_uint(f);
    unsigned r = (u + 0x7fffu + ((u >> 16) & 1u)) >> 16;
    return (short)r;
}
__device__ __forceinline__ float bf2f(short s) {
    return __uint_as_float(((unsigned)(unsigned short)s) << 16);
}

// ======================================================================
__global__ void k_transpose(const float* __restrict__ in, float* __restrict__ out) {
    int idx = blockIdx.x * 256 + threadIdx.x;
    int n = idx & 255;
    int c = (idx >> 8) % INCH;
    int b = idx / (INCH * NTOK);
    out[idx] = in[(size_t)b * INCH * NTOK + (size_t)n * INCH + c];
}

__global__ __launch_bounds__(256) void k_proj(const float* __restrict__ A,
                                              const float* __restrict__ W,
                                              const float* __restrict__ bias,
                                              float* __restrict__ out, int O) {
    int p = threadIdx.x;
    int o = blockIdx.x, b = blockIdx.y;
    const float* a = A + (size_t)b * INCH * NTOK + p;
    const float* w = W + (size_t)o * INCH;
    float acc = bias[o];
    for (int c = 0; c < INCH; ++c) acc = fmaf(a[(size_t)c * NTOK], w[c], acc);
    out[((size_t)b * O + o) * NTOK + p] = acc;
}

// ---- convT v2: W repack (tiled transpose) ----
// W is (C x M) row-major, M = O*K*K. WP[m/NT][c][m%NT]
template <int NT>
__global__ __launch_bounds__(256) void k_wcvprep(const float* __restrict__ W,
                                                 float* __restrict__ WP, int C, int M) {
    __shared__ float t[32][33];
    int c0 = blockIdx.x * 32, m0 = blockIdx.y * 32;
    int tx = threadIdx.x & 31, ty = threadIdx.x >> 5;
#pragma unroll
    for (int r = 0; r < 4; ++r) {
        int cl = ty + r * 8;
        t[cl][tx] = W[(size_t)(c0 + cl) * M + m0 + tx];
    }
    __syncthreads();
    for (int i = threadIdx.x; i < 1024; i += 256) {
        int ml = i % NT;
        int tmp = i / NT;
        int cl = tmp & 31;
        int mh = tmp >> 5;
        WP[(size_t)(m0 / NT + mh) * C * NT + (size_t)(c0 + cl) * NT + ml] = t[cl][mh * NT + ml];
    }
}

// ---- convT v2 main: X-stationary LDS GEMM ----
template <int NT, int CCH, int K>
__global__ __launch_bounds__(256) void k_convt2(const float* __restrict__ X,
                                                const float* __restrict__ WP,
                                                const float* __restrict__ bias,
                                                float* __restrict__ out,
                                                int C, int O) {
    __shared__ float sX[CCH * 256];
    int tid = threadIdx.x;
    int nt = blockIdx.x, b = blockIdx.y;
    float acc[NT];
#pragma unroll
    for (int j = 0; j < NT; ++j) acc[j] = 0.f;
    const float* Xb = X + (size_t)b * C * 256;
    for (int cc = 0; cc < C; cc += CCH) {
        __syncthreads();
        const f32x4* Xg4 = (const f32x4*)(Xb + (size_t)cc * 256);
        f32x4* s4 = (f32x4*)sX;
        for (int i = tid; i < CCH * 64; i += 256) s4[i] = Xg4[i];
        __syncthreads();
        const float* wr = WP + ((size_t)nt * C + cc) * NT;
        for (int c = 0; c < CCH; ++c) {
            float xv = sX[c * 256 + tid];
            const float* w = wr + c * NT;
#pragma unroll
            for (int j = 0; j < NT; ++j) acc[j] = fmaf(xv, w[j], acc[j]);
        }
    }
    int h = tid >> 4, w = tid & 15;
    int S = 16 * K;
#pragma unroll
    for (int j = 0; j < NT; ++j) {
        int m = nt * NT + j;
        int o = m / (K * K);
        int ij = m - o * (K * K);
        int ii = ij / K, jj = ij - ii * K;
        out[((size_t)b * O + o) * (size_t)(S * S) + (h * K + ii) * S + (w * K + jj)] =
            acc[j] + bias[o];
    }
}

// ---- down-conv v2: W repack (tiled transpose) ----
__global__ __launch_bounds__(256) void k_wdprep(const float* __restrict__ W,
                                                float* __restrict__ WP) {
    __shared__ float t[32][33];
    int k0 = blockIdx.x * 32, o0 = blockIdx.y * 32;
    int tx = threadIdx.x & 31, ty = threadIdx.x >> 5;
#pragma unroll
    for (int r = 0; r < 4; ++r) {
        int orow = ty + r * 8;
        t[orow][tx] = W[(size_t)(o0 + orow) * 9216 + k0 + tx];
    }
    __syncthreads();
#pragma unroll
    for (int r = 0; r < 4; ++r) {
        int krow = ty + r * 8;
        int o = o0 + tx;
        WP[(size_t)(o >> 6) * 589824 + (size_t)(k0 + krow) * 64 + (o & 63)] = t[tx][krow];
    }
}

// ---- down-conv v2 main: X-stationary LDS, parity-decomposed layout ----
__global__ __launch_bounds__(256) void k_down2(const float* __restrict__ X,
                                               const float* __restrict__ WP,
                                               float* __restrict__ part) {
    __shared__ float sX[64 * 256];              // 64 KB
    int tid = threadIdx.x;
    int ot = blockIdx.x, kc = blockIdx.y, b = blockIdx.z;
    int c0 = kc * 64;
    const float* Xg = X + ((size_t)b * 1024 + c0) * 256;
    for (int i = tid; i < 16384; i += 256) {
        int c = i >> 8, px = i & 255;
        int sy = px >> 4, sx = px & 15;
        int par = (sy & 1) * 2 + (sx & 1);
        sX[(c * 4 + par) * 64 + (sy >> 1) * 8 + (sx >> 1)] = Xg[i];
    }
    __syncthreads();
    int lane = tid & 63;
    int w = __builtin_amdgcn_readfirstlane(tid >> 6);
    int oh = lane >> 3, ow = lane & 7;
    int loff[9]; float lmsk[9];
#pragma unroll
    for (int kh = 0; kh < 3; ++kh)
#pragma unroll
        for (int kw = 0; kw < 3; ++kw) {
            int py = (kh == 1) ? 0 : 1;
            int pxp = (kw == 1) ? 0 : 1;
            int u = oh - ((kh == 0) ? 1 : 0);
            int v = ow - ((kw == 0) ? 1 : 0);
            float m = (u >= 0 && v >= 0) ? 1.f : 0.f;
            if (u < 0) u = 0;
            if (v < 0) v = 0;
            loff[kh * 3 + kw] = (py * 2 + pxp) * 64 + u * 8 + v;
            lmsk[kh * 3 + kw] = m;
        }
    float acc[16];
#pragma unroll
    for (int j = 0; j < 16; ++j) acc[j] = 0.f;
    const float* wb = WP + (size_t)ot * 589824 + (size_t)c0 * 576 + w * 16;
    for (int c = 0; c < 64; ++c) {
        const float* xb = sX + c * 256;
        const float* wc = wb + (size_t)c * 576;
#pragma unroll
        for (int tap = 0; tap < 9; ++tap) {
            float xv = xb[loff[tap]] * lmsk[tap];
            const float* wr = wc + tap * 64;
#pragma unroll
            for (int j = 0; j < 16; ++j) acc[j] = fmaf(xv, wr[j], acc[j]);
        }
    }
    float* pp = part + ((size_t)((kc * 2 + b) * 1024 + ot * 64 + w * 16)) * 64 + lane;
#pragma unroll
    for (int j = 0; j < 16; ++j) pp[(size_t)j * 64] = acc[j];
}

// ---- down-conv v2: K-split reduction + bias ----
__global__ __launch_bounds__(256) void k_downred(const float* __restrict__ part,
                                                 const float* __restrict__ bias,
                                                 float* __restrict__ out) {
    int idx = blockIdx.x * 256 + threadIdx.x;   // < 131072 == b*65536 + o*64 + px
    int o = (idx >> 6) & 1023;
    int b = idx >> 16;
    int px = idx & 63;
    float s = bias[o];
#pragma unroll
    for (int kcs = 0; kcs < 16; ++kcs)
        s += part[((size_t)(kcs * 2 + b) * 1024 + o) * 64 + px];
    out[idx] = s;
}

// fused concat -> bf16 CHANNELS-LAST, 8 ch per thread (vectorized 16B writes,
// 8-deep independent read chains instead of 1-per-thread scattered loads)
__global__ __launch_bounds__(256) void k_fusedcat_bf8(const float* __restrict__ f0,
                                                      const float* __restrict__ f1,
                                                      const float* __restrict__ f2,
                                                      const float* __restrict__ f3,
                                                      short* __restrict__ out) {
    int idx = blockIdx.x * 256 + threadIdx.x;       // < 2883584 = 2*4096*352
    int c8i = idx % 352;
    int t = idx / 352;                              // (b,pos) linear, < 8192
    int pos = t & 4095;
    int b = t >> 12;
    int ch0 = c8i * 8;
    bf16x8 o;
    if (ch0 < 256) {
        const float* src = f0 + ((size_t)(b * 256 + ch0)) * 4096 + pos;
#pragma unroll
        for (int k = 0; k < 8; ++k) o[k] = f2bf(src[(size_t)k * 4096]);
    } else {
        const float* src; int sh, cb;
        if (ch0 < 768)       { src = f1; cb = b * 512 + (ch0 - 256);  sh = 32; }
        else if (ch0 < 1792) { src = f2; cb = b * 1024 + (ch0 - 768); sh = 16; }
        else                 { src = f3; cb = b * 1024 + (ch0 - 1792); sh = 8; }
        int y = pos >> 6, x = pos & 63;
        float r = (float)(sh - 1) / 63.0f;
        float cy = y * r, cx = x * r;
        int i0 = (int)cy; if (i0 > sh - 2) i0 = sh - 2;
        int j0 = (int)cx; if (j0 > sh - 2) j0 = sh - 2;
        float ty = cy - (float)i0, tx = cx - (float)j0;
        int pl = sh * sh;
        const float* s0 = src + (size_t)cb * pl + i0 * sh + j0;
#pragma unroll
        for (int k = 0; k < 8; ++k) {
            const float* sp = s0 + (size_t)k * pl;
            float v00 = sp[0], v01 = sp[1], v10 = sp[sh], v11 = sp[sh + 1];
            float c0 = v00 + ty * (v10 - v00);
            float c1 = v01 + ty * (v11 - v01);
            o[k] = f2bf(c0 + tx * (c1 - c0));
        }
    }
    *(bf16x8*)(out + (size_t)t * 2816 + ch0) = o;
}

// fuse weight prep: bf16 B-fragment order for 16x16x32 MFMA.
__global__ void k_wfuseprep(const float* __restrict__ w, short* __restrict__ wb) {
    int idx = blockIdx.x * 256 + threadIdx.x;       // < 720896
    int j = idx & 7;
    int lane = (idx >> 3) & 63;
    int ntile = (idx >> 9) & 15;
    int chunk = idx >> 13;                          // < 88
    int oc = ntile * 16 + (lane & 15);
    int c = chunk * 32 + (lane >> 4) * 8 + j;
    wb[idx] = f2bf(w[(size_t)oc * 2816 + c]);
}

// fuse GEMM on MFMA bf16: M=8192 px, N=256 oc, K=2816.
__global__ __launch_bounds__(256) void k_fuse_mfma(const short* __restrict__ A,
                                                   const bf16x8* __restrict__ WB,
                                                   const float* __restrict__ bias,
                                                   short* __restrict__ out) {
    int tid = threadIdx.x;
    int lane = tid & 63, w = tid >> 6;
    int row0 = blockIdx.x * 16;                     // global px row of tile
    int l15 = lane & 15, q = lane >> 4;
    int arow = row0 + l15;
    f32x4 acc[4];
#pragma unroll
    for (int nn = 0; nn < 4; ++nn) acc[nn] = (f32x4){0.f, 0.f, 0.f, 0.f};
    const short* arp = A + (size_t)arow * 2816 + q * 8;
    for (int chunk = 0; chunk < 88; ++chunk) {
        bf16x8 a = *(const bf16x8*)(arp + chunk * 32);
        const bf16x8* wbp = WB + ((size_t)(chunk * 16 + w * 4) * 64) + lane;
#pragma unroll
        for (int nn = 0; nn < 4; ++nn) {
            bf16x8 bf = wbp[nn * 64];
            acc[nn] = __builtin_amdgcn_mfma_f32_16x16x32_bf16(a, bf, acc[nn], 0, 0, 0);
        }
    }
#pragma unroll
    for (int nn = 0; nn < 4; ++nn) {
        int oc = (w * 4 + nn) * 16 + l15;
        float bs = bias[oc];
#pragma unroll
        for (int r = 0; r < 4; ++r) {
            int m = q * 4 + r;
            out[(size_t)(row0 + m) * 256 + oc] = f2bf(fmaxf(acc[nn][r] + bs, 0.f));
        }
    }
}

// bilinear 64->224 on bf16 channels-last, 8 ch per thread
__global__ void k_resize224bf2(const short* __restrict__ in, short* __restrict__ out) {
    int idx = blockIdx.x * 256 + threadIdx.x;       // < 3211264
    int c8 = (idx & 31) * 8;
    int p = idx >> 5;                               // < 100352
    int b = p / NP;
    int pos = p - b * NP;
    int y = pos / HW, x = pos - y * HW;
    const float r = (float)(63.0 / 223.0);
    float cy = y * r, cx = x * r;
    int i0 = (int)cy; if (i0 > 62) i0 = 62;
    int j0 = (int)cx; if (j0 > 62) j0 = 62;
    float ty = cy - (float)i0, tx = cx - (float)j0;
    const short* base = in + ((size_t)b * 4096) * 256 + c8;
    const bf16x8 v00 = *(const bf16x8*)(base + (size_t)(i0 * 64 + j0) * 256);
    const bf16x8 v01 = *(const bf16x8*)(base + (size_t)(i0 * 64 + j0 + 1) * 256);
    const bf16x8 v10 = *(const bf16x8*)(base + (size_t)((i0 + 1) * 64 + j0) * 256);
    const bf16x8 v11 = *(const bf16x8*)(base + (size_t)((i0 + 1) * 64 + j0 + 1) * 256);
    bf16x8 o;
#pragma unroll
    for (int k = 0; k < 8; ++k) {
        float a00 = bf2f(v00[k]), a01 = bf2f(v01[k]);
        float a10 = bf2f(v10[k]), a11 = bf2f(v11[k]);
        float c0 = a00 + ty * (a10 - a00);
        float c1 = a01 + ty * (a11 - a01);
        o[k] = f2bf(c0 + tx * (c1 - c0));
    }
    *(bf16x8*)(out + ((size_t)b * NP + pos) * 256 + c8) = o;
}

// conv1 weight prep: BN-fold + bf16 + MFMA B-fragment order.
__global__ void k_w1prep(const float* __restrict__ w, const float* __restrict__ bias,
                         const float* __restrict__ g, const float* __restrict__ bb,
                         const float* __restrict__ m, const float* __restrict__ v,
                         short* __restrict__ wb, float* __restrict__ shift) {
    int idx = blockIdx.x * 256 + threadIdx.x;      // < 294912
    int j = idx & 7;
    int lane = (idx >> 3) & 63;
    int nt = (idx >> 9) & 7;
    int tc = idx >> 12;
    int tap = tc % 9, chunk = tc / 9;
    int oc = nt * 16 + (lane & 15);
    int c = chunk * 32 + (lane >> 4) * 8 + j;
    float s = g[oc] * rsqrtf(v[oc] + 1e-5f);
    wb[idx] = f2bf(w[((size_t)oc * 256 + c) * 9 + tap] * s);
    if (idx < 128) {
        float si = g[idx] * rsqrtf(v[idx] + 1e-5f);
        shift[idx] = (bias[idx] - m[idx]) * si + bb[idx];
    }
}

// conv1 as implicit GEMM on MFMA bf16.
__global__ __launch_bounds__(256) void k_conv1mfma(const short* __restrict__ X,
                                                   const bf16x8* __restrict__ WB,
                                                   const float* __restrict__ shift,
                                                   float* __restrict__ out) {
    int tid = threadIdx.x;
    int lane = tid & 63, w = tid >> 6;
    int t = blockIdx.x;
    int b = blockIdx.y;
    int ty0 = (t / 28) * 16, tx0 = (t % 28) * 8;
    int l15 = lane & 15, q = lane >> 4;
    int loc0 = w * 32 + l15;
    int loc1 = loc0 + 16;
    int py0 = ty0 + (loc0 >> 3), px0 = tx0 + (loc0 & 7);
    int py1 = ty0 + (loc1 >> 3), px1 = tx0 + (loc1 & 7);
    int csub = q * 8;
    f32x4 acc0[8], acc1[8];
#pragma unroll
    for (int nt = 0; nt < 8; ++nt) {
        acc0[nt] = (f32x4){0.f, 0.f, 0.f, 0.f};
        acc1[nt] = (f32x4){0.f, 0.f, 0.f, 0.f};
    }
    const short* Xb = X + (size_t)b * NP * 256;
    const bf16x8 zv = {0, 0, 0, 0, 0, 0, 0, 0};
    for (int chunk = 0; chunk < 8; ++chunk) {
        int c0 = chunk * 32 + csub;
#pragma unroll
        for (int tap = 0; tap < 9; ++tap) {
            int dy = tap / 3 - 1, dx = tap % 3 - 1;
            int sy0 = py0 + dy, sx0 = px0 + dx;
            int sy1 = py1 + dy, sx1 = px1 + dx;
            bf16x8 a0 = zv, a1 = zv;
            if ((unsigned)sy0 < HW && (unsigned)sx0 < HW)
                a0 = *(const bf16x8*)(Xb + ((size_t)sy0 * HW + sx0) * 256 + c0);
            if ((unsigned)sy1 < HW && (unsigned)sx1 < HW)
                a1 = *(const bf16x8*)(Xb + ((size_t)sy1 * HW + sx1) * 256 + c0);
            const bf16x8* wbp = WB + (size_t)((chunk * 9 + tap) * 8) * 64 + lane;
#pragma unroll
            for (int nt = 0; nt < 8; ++nt) {
                bf16x8 bf = wbp[nt * 64];
                acc0[nt] = __builtin_amdgcn_mfma_f32_16x16x32_bf16(a0, bf, acc0[nt], 0, 0, 0);
                acc1[nt] = __builtin_amdgcn_mfma_f32_16x16x32_bf16(a1, bf, acc1[nt], 0, 0, 0);
            }
        }
    }
    int m0 = w * 32, m1 = w * 32 + 16;
#pragma unroll
    for (int nt = 0; nt < 8; ++nt) {
        int oc = nt * 16 + l15;
        float sh = shift[oc];
        float* ob = out + ((size_t)(b * 128 + oc)) * NP;
#pragma unroll
        for (int r = 0; r < 4; ++r) {
            int md = q * 4 + r;
            int lm = m0 + md;
            int py = ty0 + (lm >> 3), px = tx0 + (lm & 7);
            ob[py * HW + px] = fmaxf(acc0[nt][r] + sh, 0.f);
            lm = m1 + md;
            py = ty0 + (lm >> 3); px = tx0 + (lm & 7);
            ob[py * HW + px] = fmaxf(acc1[nt][r] + sh, 0.f);
        }
    }
}

// ---- conv3 v3: weight repack (O,C,3,3) -> WP[c][tap][o] ----
__global__ void k_wc3prep(const float* __restrict__ W, float* __restrict__ WP,
                          int C, int O) {
    int idx = blockIdx.x * 256 + threadIdx.x;
    if (idx >= C * 9 * O) return;
    int o = idx % O;
    int t = idx / O;
    int tap = t % 9, c = t / 9;
    WP[idx] = W[((size_t)o * C + c) * 9 + tap];
}

// ---- conv3 v3 main: K-split, all-O-per-block, 32x8 px tile (bank-conflict-free) ----
template <int O, int CB>
__global__ __launch_bounds__(256) void k_conv3v3(const float* __restrict__ in,
                                                 const float* __restrict__ WP,
                                                 float* __restrict__ part, int C) {
    __shared__ float sX[8 * 360];               // 8 ch x 10 rows x 36-stride
    int tid = threadIdx.x;
    int tb = blockIdx.x, s = blockIdx.y, b = blockIdx.z;
    int ty0 = (tb / 7) * 8, tx0 = (tb % 7) * 32;
    int px = tid & 31, py = tid >> 5;
    float acc[O];
#pragma unroll
    for (int o = 0; o < O; ++o) acc[o] = 0.f;
    int c0 = s * CB;
    const float* ic = in + ((size_t)b * C + c0) * NP;
    const float* wbase = WP + (size_t)c0 * 9 * O;
    for (int cc = 0; cc < CB; cc += 8) {
        __syncthreads();
        for (int i = tid; i < 8 * 340; i += 256) {
            int c = i / 340;
            int r = i - c * 340;
            int y = r / 34, x = r - y * 34;
            int sy = ty0 + y - 1, sx = tx0 + x - 1;
            float v = 0.f;
            if ((unsigned)sy < HW && (unsigned)sx < HW)
                v = ic[(size_t)(cc + c) * NP + sy * HW + sx];
            sX[c * 360 + y * 36 + x] = v;
        }
        __syncthreads();
        const float* xb = sX + py * 36 + px;
#pragma unroll 1
        for (int c = 0; c < 8; ++c) {
            const float* xc = xb + c * 360;
            const float* wc = wbase + (size_t)(cc + c) * 9 * O;
#pragma unroll
            for (int kh = 0; kh < 3; ++kh)
#pragma unroll
                for (int kw = 0; kw < 3; ++kw) {
                    float xv = xc[kh * 36 + kw];
                    const float* wt = wc + (kh * 3 + kw) * O;
#pragma unroll
                    for (int o = 0; o < O; ++o) acc[o] = fmaf(xv, wt[o], acc[o]);
                }
        }
    }
    int gy = ty0 + py, gx = tx0 + px;
    float* ob = part + ((size_t)(s * BATCH + b) * O) * NP + (size_t)gy * HW + gx;
#pragma unroll
    for (int o = 0; o < O; ++o) ob[(size_t)o * NP] = acc[o];
}

// ---- conv3 v3: K-split reduction + bias ----
template <int O, int NS>
__global__ __launch_bounds__(256) void k_conv3red(const float* __restrict__ part,
                                                  const float* __restrict__ bias,
                                                  float* __restrict__ out) {
    int idx = blockIdx.x * 256 + threadIdx.x;   // < B*O*NP, layout (b,o,pos)
    int o = (idx / NP) % O;
    float v = bias[o];
#pragma unroll
    for (int s2 = 0; s2 < NS; ++s2)
        v += part[(size_t)idx + (size_t)s2 * (BATCH * O * NP)];
    out[idx] = v;
}

__global__ __launch_bounds__(256) void k_sim(const float* __restrict__ pe,
                                             const float* __restrict__ proto,
                                             float* __restrict__ sim) {
    int idx = blockIdx.x * 256 + threadIdx.x;
    int b = idx / NP, pos = idx - b * NP;
    const float* p = pe + (size_t)b * EMBD * NP + pos;
    float v[EMBD];
#pragma unroll
    for (int e = 0; e < EMBD; ++e) v[e] = p[(size_t)e * NP];
    const float scale = 1.0f / sqrtf(32.0f);
    float* so = sim + (size_t)b * NPROTO * NP + pos;
    for (int q = 0; q < NPROTO; ++q) {
        float acc = 0.f;
#pragma unroll
        for (int e = 0; e < EMBD; ++e) acc = fmaf(v[e], proto[q * EMBD + e], acc);
        so[(size_t)q * NP] = acc * scale;
    }
}

__global__ void k_init(float* acc) { if (threadIdx.x < 8) acc[threadIdx.x] = 0.f; }

__device__ __forceinline__ float block_reduce_sum(float v) {
    __shared__ float sh[4];
#pragma unroll
    for (int off = 32; off > 0; off >>= 1) v += __shfl_down(v, off);
    int lane = threadIdx.x & 63, wv = threadIdx.x >> 6;
    if (lane == 0) sh[wv] = v;
    __syncthreads();
    return (threadIdx.x == 0) ? (sh[0] + sh[1] + sh[2] + sh[3]) : 0.f;
}

__global__ __launch_bounds__(256) void k_edge(const float* __restrict__ pe,
                                              float* __restrict__ edge,
                                              float* __restrict__ acc) {
    int idx = blockIdx.x * 256 + threadIdx.x;
    int b = idx / NP, pos = idx - b * NP;
    int h = pos / HW, w = pos - h * HW;
    int wn = (w < HW - 1) ? w : HW - 2;
    int hn = (h < HW - 1) ? h : HW - 2;
    const float* pb = pe + (size_t)b * EMBD * NP;
    float sx = 0.f, sy = 0.f;
#pragma unroll 4
    for (int e = 0; e < EMBD; ++e) {
        const float* p = pb + (size_t)e * NP;
        sx += fabsf(p[h * HW + wn] - p[h * HW + wn + 1]);
        sy += fabsf(p[hn * HW + w] - p[hn * HW + HW + w]);
    }
    float ev = (sx + sy) * (0.5f / 32.0f);
    edge[idx] = ev;
    float tot = block_reduce_sum(ev);
    if (threadIdx.x == 0) atomicAdd(acc, tot);
}

__global__ void k_smooth(const float* __restrict__ sin_, const float* __restrict__ edge,
                         const float* __restrict__ acc, float* __restrict__ sout) {
    int idx = blockIdx.x * 256 + threadIdx.x;
    int pos = idx % NP;
    int bp = idx / NP;
    int b = bp >> 6;
    int h = pos / HW, w = pos - h * HW;
    float mean = acc[0] * (1.0f / 100352.0f);
    float m = (edge[(size_t)b * NP + pos] > mean) ? 1.f : 0.f;
    const float* sc = sin_ + (size_t)bp * NP;
    float s = 0.f;
#pragma unroll
    for (int dy = -1; dy <= 1; ++dy) {
        int yy = h + dy;
        if (yy < 0 || yy >= HW) continue;
#pragma unroll
        for (int dx = -1; dx <= 1; ++dx) {
            int xx = w + dx;
            if (xx < 0 || xx >= HW) continue;
            s += sc[yy * HW + xx];
        }
    }
    float c = sc[pos];
    sout[idx] = m * c + (1.f - m) * (s * (1.0f / 9.0f));
}

__global__ __launch_bounds__(256) void k_entropy(const float* __restrict__ sim,
                                                 float* __restrict__ acc) {
    int idx = blockIdx.x * 256 + threadIdx.x;
    int b = idx / NP, pos = idx - b * NP;
    const float* s = sim + (size_t)b * NPROTO * NP + pos;
    float v[NPROTO];
    float mx = -3.0e38f;
#pragma unroll
    for (int q = 0; q < NPROTO; ++q) { v[q] = s[(size_t)q * NP]; mx = fmaxf(mx, v[q]); }
    float sum = 0.f;
#pragma unroll
    for (int q = 0; q < NPROTO; ++q) { float e = expf(v[q] - mx); v[q] = e; sum += e; }
    float inv = 1.f / sum;
    float ent = 0.f;
#pragma unroll
    for (int q = 0; q < NPROTO; ++q) {
        float a = v[q] * inv;
        ent -= a * logf(a + 1e-8f);
    }
    float tot = block_reduce_sum(ent);
    if (threadIdx.x == 0) atomicAdd(acc + 1, tot);
}

__global__ void k_bb(const float* __restrict__ pb, const float* __restrict__ bs,
                     float* __restrict__ bbuf, float* __restrict__ obb) {
    int t = threadIdx.x;
    if (t < NPROTO) {
        float v = 1.f + tanhf(pb[t]) * bs[0];
        bbuf[t] = v;
        obb[t] = v;
        obb[NPROTO + t] = v;
    }
}

__global__ __launch_bounds__(256) void k_actsm(const float* __restrict__ sim,
                                               const float* __restrict__ bb,
                                               float* __restrict__ act,
                                               float* __restrict__ bgain) {
    int idx = blockIdx.x * 256 + threadIdx.x;
    int b = idx / NP, pos = idx - b * NP;
    const float* s = sim + (size_t)b * NPROTO * NP + pos;
    float v[NPROTO];
    float mx = -3.0e38f;
#pragma unroll
    for (int q = 0; q < NPROTO; ++q) { v[q] = s[(size_t)q * NP]; mx = fmaxf(mx, v[q]); }
    float sum = 0.f;
#pragma unroll
    for (int q = 0; q < NPROTO; ++q) { float e = expf(v[q] - mx); v[q] = e; sum += e; }
    float inv = 1.f / sum;
    float* a = act + (size_t)b * NPROTO * NP + pos;
    float bg = 0.f;
#pragma unroll
    for (int q = 0; q < NPROTO; ++q) {
        float p = v[q] * inv;
        a[(size_t)q * NP] = p;
        bg = fmaf(p, bb[q], bg);
    }
    bgain[idx] = bg;
}

__global__ void k_headprep(const float* __restrict__ w1, const float* __restrict__ b1,
                           const float* __restrict__ g1, const float* __restrict__ be1,
                           const float* __restrict__ m1, const float* __restrict__ v1,
                           const float* __restrict__ w2, const float* __restrict__ b2,
                           const float* __restrict__ g2, const float* __restrict__ be2,
                           const float* __restrict__ m2, const float* __restrict__ v2,
                           float* __restrict__ wf) {
    int oc = blockIdx.x * 256 + threadIdx.x;
    if (oc >= 512) return;
    float s1 = g1[oc] * rsqrtf(v1[oc] + 1e-5f);
#pragma unroll
    for (int k = 0; k < 9; ++k) wf[oc * 9 + k] = w1[oc * 9 + k] * s1;
    wf[41472 + oc] = (b1[oc] - m1[oc]) * s1 + be1[oc];
    float s2 = g2[oc] * rsqrtf(v2[oc] + 1e-5f);
    int g = oc >> 3, j = oc & 7;
#pragma unroll
    for (int icc = 0; icc < 8; ++icc)
#pragma unroll
        for (int k = 0; k < 9; ++k)
            wf[4608 + (size_t)g * 576 + icc * 72 + j * 9 + k] = w2[((size_t)oc * 8 + icc) * 9 + k] * s2;
    wf[41984 + oc] = (b2[oc] - m2[oc]) * s2 + be2[oc];
}

// fused 3-layer grouped heads, 16x16 out-tile (R4 verified version).
__global__ __launch_bounds__(256) void k_heads(
    const float* __restrict__ act, const float* __restrict__ wf,
    const float* __restrict__ w3, const float* __restrict__ b3,
    float* __restrict__ res) {
    __shared__ float sA[22 * 24];           // origin (oy0-3, ox0-3), stride 24
    __shared__ float sH1[8][20 * 22];       // origin (oy0-2, ox0-2), stride 22
    __shared__ float sH2[8][18 * 18];       // origin (oy0-1, ox0-1), stride 18
    int tid = threadIdx.x;
    int tile = blockIdx.x, g = blockIdx.y, b = blockIdx.z;
    int oy0 = (tile / 14) * 16, ox0 = (tile % 14) * 16;
    const float* ain = act + (size_t)(b * NPROTO + g) * NP;

    for (int i = tid; i < 484; i += 256) {
        int y = i / 22, x = i - y * 22;
        int gy = oy0 - 3 + y, gx = ox0 - 3 + x;
        float v = 0.f;
        if ((unsigned)gy < HW && (unsigned)gx < HW) v = ain[gy * HW + gx];
        sA[y * 24 + x] = v;
    }
    __syncthreads();

    // stage1: 20x20, 1 px/thread
    const float* b1f = wf + 41472 + g * 8;
    for (int i = tid; i < 400; i += 256) {
        int y = i / 20, x = i - y * 20;
        int gy = oy0 - 2 + y, gx = ox0 - 2 + x;
        float keep = ((unsigned)gy < HW && (unsigned)gx < HW) ? 1.f : 0.f;
        const float* s0 = sA + y * 24 + x;
        float r0 = s0[0],  r1 = s0[1],  r2 = s0[2];
        float r3 = s0[24], r4 = s0[25], r5 = s0[26];
        float r6 = s0[48], r7 = s0[49], r8 = s0[50];
#pragma unroll
        for (int j = 0; j < 8; ++j) {
            const float* w = wf + (g * 8 + j) * 9;
            float v = fmaf(r0, w[0], fmaf(r1, w[1], fmaf(r2, w[2],
                      fmaf(r3, w[3], fmaf(r4, w[4], fmaf(r5, w[5],
                      fmaf(r6, w[6], fmaf(r7, w[7], fmaf(r8, w[8], b1f[j])))))))));
            sH1[j][y * 22 + x] = fmaxf(v, 0.f) * keep;
        }
    }
    __syncthreads();

    // stage2: 18x18 as 18x9 pixel pairs, f32x2 packed
    const float* w2f = wf + 4608 + (size_t)g * 576;
    const float* b2f = wf + 41984 + g * 8;
    if (tid < 162) {
        int y2 = tid / 9, xp = (tid - y2 * 9) * 2;
        f32x2 a2[8];
#pragma unroll
        for (int j = 0; j < 8; ++j) { float bv = b2f[j]; a2[j] = (f32x2){bv, bv}; }
#pragma unroll
        for (int icc = 0; icc < 8; ++icc) {
            const float* s0 = &sH1[icc][y2 * 22 + xp];
            f32x2 t[9];
#pragma unroll
            for (int r = 0; r < 3; ++r) {
                float f0 = s0[r * 22], f1 = s0[r * 22 + 1];
                float f2 = s0[r * 22 + 2], f3 = s0[r * 22 + 3];
                t[r * 3 + 0] = (f32x2){f0, f1};
                t[r * 3 + 1] = (f32x2){f1, f2};
                t[r * 3 + 2] = (f32x2){f2, f3};
            }
            const float* wr = w2f + icc * 72;
#pragma unroll
            for (int j = 0; j < 8; ++j) {
                const float* wj = wr + j * 9;
#pragma unroll
                for (int k = 0; k < 9; ++k) {
                    float wv = wj[k];
                    a2[j] = __builtin_elementwise_fma(t[k], (f32x2){wv, wv}, a2[j]);
                }
            }
        }
        int gy = oy0 - 1 + y2;
        int gx0 = ox0 - 1 + xp;
        float k0 = ((unsigned)gy < HW && (unsigned)gx0 < HW) ? 1.f : 0.f;
        float k1 = ((unsigned)gy < HW && (unsigned)(gx0 + 1) < HW) ? 1.f : 0.f;
        f32x2 kp = (f32x2){k0, k1};
        const f32x2 z2 = (f32x2){0.f, 0.f};
#pragma unroll
        for (int j = 0; j < 8; ++j) {
            f32x2 v = __builtin_elementwise_max(a2[j], z2) * kp;
            sH2[j][y2 * 18 + xp] = v.x;
            sH2[j][y2 * 18 + xp + 1] = v.y;
        }
    }
    __syncthreads();

    // stage3: 16x16 as 16x8 pairs, f32x2 packed
    if (tid < 128) {
        int y3 = tid >> 3, xp = (tid & 7) * 2;
        float bv = b3[g];
        f32x2 a2 = (f32x2){bv, bv};
#pragma unroll
        for (int icc = 0; icc < 8; ++icc) {
            const float* s0 = &sH2[icc][y3 * 18 + xp];
            const float* w = w3 + (size_t)(g * 8 + icc) * 9;
#pragma unroll
            for (int r = 0; r < 3; ++r) {
                float f0 = s0[r * 18], f1 = s0[r * 18 + 1];
                float f2 = s0[r * 18 + 2], f3 = s0[r * 18 + 3];
                float w0 = w[r * 3], w1 = w[r * 3 + 1], w2v = w[r * 3 + 2];
                a2 = __builtin_elementwise_fma((f32x2){f0, f1}, (f32x2){w0, w0}, a2);
                a2 = __builtin_elementwise_fma((f32x2){f1, f2}, (f32x2){w1, w1}, a2);
                a2 = __builtin_elementwise_fma((f32x2){f2, f3}, (f32x2){w2v, w2v}, a2);
            }
        }
        float* rp = res + (size_t)(b * NPROTO + g) * NP + (size_t)(oy0 + y3) * HW + (ox0 + xp);
        rp[0] = a2.x;
        rp[1] = a2.y;
    }
}

__global__ __launch_bounds__(256) void k_final(const float* __restrict__ act,
                                               const float* __restrict__ res,
                                               const float* __restrict__ bgain,
                                               const float* __restrict__ rscale,
                                               float* __restrict__ owt,
                                               float* __restrict__ oibm) {
    int idx = blockIdx.x * 256 + threadIdx.x;
    int b = idx / NP, pos = idx - b * NP;
    const float* a = act + (size_t)b * NPROTO * NP + pos;
    const float* r = res + (size_t)b * NPROTO * NP + pos;
    float wt = 0.f;
#pragma unroll
    for (int q = 0; q < NPROTO; ++q) wt = fmaf(a[(size_t)q * NP], r[(size_t)q * NP], wt);
    owt[idx] = wt;
    float gn = bgain[idx] * (1.f + tanhf(wt) * rscale[0]);
    gn = fminf(fmaxf(gn, 0.5f), 2.0f);
    oibm[idx] = gn;
}

__global__ void k_entfinal(const float* __restrict__ acc, float* __restrict__ o) {
    if (threadIdx.x == 0) o[0] = acc[1] * (1.0f / 100352.0f);
}

// ======================================================================
extern "C" void kernel_launch(void* const* d_in, const int* in_sizes, int n_in,
                              void* d_out, int out_size, void* d_ws, size_t ws_size,
                              hipStream_t stream) {
    const float* tokens[4] = {(const float*)d_in[0], (const float*)d_in[1],
                              (const float*)d_in[2], (const float*)d_in[3]};
    const float* proj_w[4] = {(const float*)d_in[4], (const float*)d_in[6],
                              (const float*)d_in[8], (const float*)d_in[10]};
    const float* proj_b[4] = {(const float*)d_in[5], (const float*)d_in[7],
                              (const float*)d_in[9], (const float*)d_in[11]};
    const float* up_w0 = (const float*)d_in[12]; const float* up_b0 = (const float*)d_in[13];
    const float* up_w1 = (const float*)d_in[14]; const float* up_b1 = (const float*)d_in[15];
    const float* down_w3 = (const float*)d_in[16]; const float* down_b3 = (const float*)d_in[17];
    const float* fuse_w = (const float*)d_in[18]; const float* fuse_b = (const float*)d_in[19];
    const float* pe_w1 = (const float*)d_in[20]; const float* pe_b1 = (const float*)d_in[21];
    const float* pe_bn_g = (const float*)d_in[22]; const float* pe_bn_b = (const float*)d_in[23];
    const float* pe_bn_m = (const float*)d_in[24]; const float* pe_bn_v = (const float*)d_in[25];
    const float* pe_w2 = (const float*)d_in[26]; const float* pe_b2 = (const float*)d_in[27];
    const float* prototypes = (const float*)d_in[28];
    const float* proto_biases = (const float*)d_in[29];
    const float* bias_scale = (const float*)d_in[30];
    const float* smooth_w = (const float*)d_in[31]; const float* smooth_b = (const float*)d_in[32];
    const float* hw1 = (const float*)d_in[33]; const float* hb1 = (const float*)d_in[34];
    const float* hg1 = (const float*)d_in[35]; const float* hbe1 = (const float*)d_in[36];
    const float* hm1 = (const float*)d_in[37]; const float* hv1 = (const float*)d_in[38];
    const float* hw2 = (const float*)d_in[39]; const float* hb2 = (const float*)d_in[40];
    const float* hg2 = (const float*)d_in[41]; const float* hbe2 = (const float*)d_in[42];
    const float* hm2 = (const float*)d_in[43]; const float* hv2 = (const float*)d_in[44];
    const float* hw3 = (const float*)d_in[45]; const float* hb3 = (const float*)d_in[46];
    const float* rscale = (const float*)d_in[47];
    (void)in_sizes; (void)n_in; (void)out_size; (void)ws_size;

    float* ws = (float*)d_ws;
    float* FEATS[4] = {ws + OFF_FEATS0, ws + OFF_FEATS1, ws + OFF_FEATS2, ws + OFF_FEATS3};
    float* TOKT = ws + OFF_TOKT;
    float* F0 = ws + OFF_F0; float* F1 = ws + OFF_F1; float* F3 = ws + OFF_F3;
    short* FUSEDBF = (short*)(ws + OFF_FUSEDBF);
    short* P64C = (short*)(ws + OFF_P64C);
    short* P224C = (short*)(ws + OFF_P224C);
    short* WB = (short*)(ws + OFF_WB);
    short* WFUSE = (short*)(ws + OFF_WFUSE);
    float* SHIFT = ws + OFF_SHIFT;
    float* T1 = ws + OFF_T1;
    float* SIMA = ws + OFF_SIMA; float* SIMB = ws + OFF_SIMB;
    float* EDGE = ws + OFF_EDGE; float* RES = ws + OFF_RES;
    float* BGAIN = ws + OFF_BGAIN; float* BBUF = ws + OFF_BB; float* ACC = ws + OFF_ACC;
    float* WF = ws + OFF_WF;
    float* WDP = ws + OFF_WD;
    float* PART = ws + OFF_PART;
    float* WCV0 = ws + OFF_WCV0;
    float* WCV1 = ws + OFF_WCV1;
    float* WC2 = ws + OFF_WC2;
    float* WSM = ws + OFF_WSM;
    float* PC2 = ws + OFF_PC2;      // conv2 partials (dead-P224C window)
    float* PSM = ws + OFF_PSM;      // smooth partials (dead-T1 window)

    float* out = (float*)d_out;
    float* o_ibm = out + O_IBM; float* o_act = out + O_ACT; float* o_bb = out + O_BB;
    float* o_wt = out + O_WT; float* o_pe = out + O_PE; float* o_ent = out + O_ENT;

    const int OCH[4] = {256, 512, 1024, 1024};
    for (int s = 0; s < 4; ++s)
        k_transpose<<<768, 256, 0, stream>>>(tokens[s], TOKT + s * 196608);
    for (int s = 0; s < 4; ++s)
        k_proj<<<dim3(OCH[s], BATCH), 256, 0, stream>>>(TOKT + s * 196608, proj_w[s], proj_b[s],
                                                        FEATS[s], OCH[s]);
    // convT v2: pack W (C x M tiled transpose), then LDS-GEMM
    k_wcvprep<16><<<dim3(8, 128), 256, 0, stream>>>(up_w0, WCV0, 256, 4096);
    k_wcvprep<8><<<dim3(16, 64), 256, 0, stream>>>(up_w1, WCV1, 512, 2048);
    k_convt2<16, 64, 4><<<dim3(256, BATCH), 256, 0, stream>>>(FEATS[0], WCV0, up_b0, F0, 256, 256);
    k_convt2<8, 64, 2><<<dim3(256, BATCH), 256, 0, stream>>>(FEATS[1], WCV1, up_b1, F1, 512, 512);
    // down-conv v2: pack W, K-split GEMM, reduce (+bias)
    k_wdprep<<<dim3(288, 32), 256, 0, stream>>>(down_w3, WDP);
    k_down2<<<dim3(16, 16, BATCH), 256, 0, stream>>>(FEATS[3], WDP, PART);
    k_downred<<<512, 256, 0, stream>>>(PART, down_b3, F3);
    // conv3 v3 weight packs (early, independent)
    k_wc3prep<<<144, 256, 0, stream>>>(pe_w2, WC2, 128, 32);
    k_wc3prep<<<144, 256, 0, stream>>>(smooth_w, WSM, 64, 64);
    k_wfuseprep<<<2816, 256, 0, stream>>>(fuse_w, WFUSE);
    k_fusedcat_bf8<<<11264, 256, 0, stream>>>(F0, F1, FEATS[2], F3, FUSEDBF);
    k_fuse_mfma<<<512, 256, 0, stream>>>(FUSEDBF, (const bf16x8*)WFUSE, fuse_b, P64C);
    // FUSEDBF dead: WB/SHIFT (inside its range) safe now
    k_w1prep<<<1152, 256, 0, stream>>>(pe_w1, pe_b1, pe_bn_g, pe_bn_b, pe_bn_m, pe_bn_v,
                                       WB, SHIFT);
    k_resize224bf2<<<12544, 256, 0, stream>>>(P64C, P224C);
    k_conv1mfma<<<dim3(392, BATCH), 256, 0, stream>>>(P224C, (const bf16x8*)WB, SHIFT, T1);
    // conv2: K-split 4 (P224C dead -> PC2 window free)
    k_conv3v3<32, 32><<<dim3(196, 4, BATCH), 256, 0, stream>>>(T1, WC2, PC2, 128);
    k_conv3red<32, 4><<<12544, 256, 0, stream>>>(PC2, pe_b2, o_pe);
    k_sim<<<392, 256, 0, stream>>>(o_pe, prototypes, SIMA);
    k_init<<<1, 64, 0, stream>>>(ACC);
    k_edge<<<392, 256, 0, stream>>>(o_pe, EDGE, ACC);
    k_smooth<<<25088, 256, 0, stream>>>(SIMA, EDGE, ACC, SIMB);
    k_smooth<<<25088, 256, 0, stream>>>(SIMB, EDGE, ACC, SIMA);
    k_entropy<<<392, 256, 0, stream>>>(SIMA, ACC);
    // smooth conv: K-split 2 (T1 dead -> PSM window free)
    k_conv3v3<64, 32><<<dim3(196, 2, BATCH), 256, 0, stream>>>(SIMA, WSM, PSM, 64);
    k_conv3red<64, 2><<<25088, 256, 0, stream>>>(PSM, smooth_b, SIMB);
    k_bb<<<1, 64, 0, stream>>>(proto_biases, bias_scale, BBUF, o_bb);
    k_actsm<<<392, 256, 0, stream>>>(SIMB, BBUF, o_act, BGAIN);
    k_headprep<<<2, 256, 0, stream>>>(hw1, hb1, hg1, hbe1, hm1, hv1,
                                      hw2, hb2, hg2, hbe2, hm2, hv2, WF);
    k_heads<<<dim3(196, 64, BATCH), 256, 0, stream>>>(o_act, WF, hw3, hb3, RES);
    k_final<<<392, 256, 0, stream>>>(o_act, RES, BGAIN, rscale, o_wt, o_ibm);
    k_entfinal<<<1, 1, 0, stream>>>(ACC, o_ent);
}

// Round 9
// 1534.376 us; speedup vs baseline: 1.0435x; 1.0435x over previous
//
#include <hip/hip_runtime.h>
#include <math.h>

// ---------------- problem constants ----------------
#define BATCH 2
#define NTOK 256
#define INCH 384
#define NP 50176          // 224*224
#define HW 224
#define NPROTO 64
#define EMBD 32

// ---------------- workspace layout (floats) ----------------
#define OFF_FEATS0   0u
#define OFF_FEATS1   131072u
#define OFF_FEATS2   393216u
#define OFF_FEATS3   917504u
#define OFF_TOKT     1441792u
#define OFF_F0       2228224u
#define OFF_F1       4325376u
#define OFF_F3       5373952u
#define OFF_FUSEDBF  5505024u      // (2,4096,2816) bf16 = 11.53M fl -> ends 17.04M
#define OFF_WD       5505024u      // down-conv packed weights (9.44M fl) — dead-FUSEDBF window
#define OFF_PART     14942208u     // down-conv K-split partials (2.10M fl) -> ends 17039360
#define OFF_P64C     28573696u     // (2,4096,256) bf16 channels-last
#define OFF_P224C    0u            // (2,224,224,256) bf16 = 12.85M fl
#define OFF_T1       25690112u     // (2,128,224,224) fp32
#define OFF_PC2      0u            // conv2 K-split partials (4x2x32xNP = 12.85M fl, dead-P224C window)
#define OFF_SIMRAW   25690112u     // raw sim (2x64xNP = 6.42M fl, dead-T1 window)
#define OFF_PSM      25690112u     // smooth-conv K-split partials (2x2x64xNP, dead after SIMRAW consumed)
#define OFF_SIMA     0u
#define OFF_SIMB     6422528u      // (unused now, kept for reference)
#define OFF_EDGE     12845056u
#define OFF_RES      13000000u
#define OFF_WB       13000000u     // conv1 MFMA weight frags (dead-RES window, written after fuse)
#define OFF_SHIFT    13200000u
#define OFF_BGAIN    19422528u
#define OFF_BB       19522880u
#define OFF_ACC      19523008u
#define OFF_WF       19523072u     // folded head weights (42496 fl)
#define OFF_WFUSE    20000000u     // fuse MFMA weight frags: 720896 bf16 = 360448 fl
#define OFF_WCV0     20500000u     // convT F0 packed W: 1048576 fl
#define OFF_WCV1     21600000u     // convT F1 packed W: 1048576 fl -> ends 22.65M
#define OFF_WC2      22700000u     // conv2 packed W [c][tap][o]: 36864 fl
#define OFF_WSM      22750000u     // smooth packed W [c][tap][o]: 36864 fl -> ends 22.79M (< T1 @25.69M)

// ---------------- output layout ----------------
#define O_IBM 0u
#define O_ACT 100352u
#define O_BB  6522880u
#define O_WT  6523008u
#define O_PE  6623360u
#define O_ENT 9834624u

typedef __attribute__((ext_vector_type(8))) short bf16x8;
typedef __attribute__((ext_vector_type(4))) float f32x4;
typedef __attribute__((ext_vector_type(2))) float f32x2;

__device__ __forceinline__ short f2bf(float f) {
    unsigned u = __float_as_uint(f);
    unsigned r = (u + 0x7fffu + ((u >> 16) & 1u)) >> 16;
    return (short)r;
}
__device__ __forceinline__ float bf2f(short s) {
    return __uint_as_float(((unsigned)(unsigned short)s) << 16);
}

// ======================================================================
__global__ void k_transpose(const float* __restrict__ in, float* __restrict__ out) {
    int idx = blockIdx.x * 256 + threadIdx.x;
    int n = idx & 255;
    int c = (idx >> 8) % INCH;
    int b = idx / (INCH * NTOK);
    out[idx] = in[(size_t)b * INCH * NTOK + (size_t)n * INCH + c];
}

__global__ __launch_bounds__(256) void k_proj(const float* __restrict__ A,
                                              const float* __restrict__ W,
                                              const float* __restrict__ bias,
                                              float* __restrict__ out, int O) {
    int p = threadIdx.x;
    int o = blockIdx.x, b = blockIdx.y;
    const float* a = A + (size_t)b * INCH * NTOK + p;
    const float* w = W + (size_t)o * INCH;
    float acc = bias[o];
    for (int c = 0; c < INCH; ++c) acc = fmaf(a[(size_t)c * NTOK], w[c], acc);
    out[((size_t)b * O + o) * NTOK + p] = acc;
}

// ---- convT v2: W repack (tiled transpose) ----
template <int NT>
__global__ __launch_bounds__(256) void k_wcvprep(const float* __restrict__ W,
                                                 float* __restrict__ WP, int C, int M) {
    __shared__ float t[32][33];
    int c0 = blockIdx.x * 32, m0 = blockIdx.y * 32;
    int tx = threadIdx.x & 31, ty = threadIdx.x >> 5;
#pragma unroll
    for (int r = 0; r < 4; ++r) {
        int cl = ty + r * 8;
        t[cl][tx] = W[(size_t)(c0 + cl) * M + m0 + tx];
    }
    __syncthreads();
    for (int i = threadIdx.x; i < 1024; i += 256) {
        int ml = i % NT;
        int tmp = i / NT;
        int cl = tmp & 31;
        int mh = tmp >> 5;
        WP[(size_t)(m0 / NT + mh) * C * NT + (size_t)(c0 + cl) * NT + ml] = t[cl][mh * NT + ml];
    }
}

// ---- convT v2 main: X-stationary LDS GEMM ----
template <int NT, int CCH, int K>
__global__ __launch_bounds__(256) void k_convt2(const float* __restrict__ X,
                                                const float* __restrict__ WP,
                                                const float* __restrict__ bias,
                                                float* __restrict__ out,
                                                int C, int O) {
    __shared__ float sX[CCH * 256];
    int tid = threadIdx.x;
    int nt = blockIdx.x, b = blockIdx.y;
    float acc[NT];
#pragma unroll
    for (int j = 0; j < NT; ++j) acc[j] = 0.f;
    const float* Xb = X + (size_t)b * C * 256;
    for (int cc = 0; cc < C; cc += CCH) {
        __syncthreads();
        const f32x4* Xg4 = (const f32x4*)(Xb + (size_t)cc * 256);
        f32x4* s4 = (f32x4*)sX;
        for (int i = tid; i < CCH * 64; i += 256) s4[i] = Xg4[i];
        __syncthreads();
        const float* wr = WP + ((size_t)nt * C + cc) * NT;
        for (int c = 0; c < CCH; ++c) {
            float xv = sX[c * 256 + tid];
            const float* w = wr + c * NT;
#pragma unroll
            for (int j = 0; j < NT; ++j) acc[j] = fmaf(xv, w[j], acc[j]);
        }
    }
    int h = tid >> 4, w = tid & 15;
    int S = 16 * K;
#pragma unroll
    for (int j = 0; j < NT; ++j) {
        int m = nt * NT + j;
        int o = m / (K * K);
        int ij = m - o * (K * K);
        int ii = ij / K, jj = ij - ii * K;
        out[((size_t)b * O + o) * (size_t)(S * S) + (h * K + ii) * S + (w * K + jj)] =
            acc[j] + bias[o];
    }
}

// ---- down-conv v2: W repack (tiled transpose) ----
__global__ __launch_bounds__(256) void k_wdprep(const float* __restrict__ W,
                                                float* __restrict__ WP) {
    __shared__ float t[32][33];
    int k0 = blockIdx.x * 32, o0 = blockIdx.y * 32;
    int tx = threadIdx.x & 31, ty = threadIdx.x >> 5;
#pragma unroll
    for (int r = 0; r < 4; ++r) {
        int orow = ty + r * 8;
        t[orow][tx] = W[(size_t)(o0 + orow) * 9216 + k0 + tx];
    }
    __syncthreads();
#pragma unroll
    for (int r = 0; r < 4; ++r) {
        int krow = ty + r * 8;
        int o = o0 + tx;
        WP[(size_t)(o >> 6) * 589824 + (size_t)(k0 + krow) * 64 + (o & 63)] = t[tx][krow];
    }
}

// ---- down-conv v2 main: X-stationary LDS, parity-decomposed layout ----
__global__ __launch_bounds__(256) void k_down2(const float* __restrict__ X,
                                               const float* __restrict__ WP,
                                               float* __restrict__ part) {
    __shared__ float sX[64 * 256];              // 64 KB
    int tid = threadIdx.x;
    int ot = blockIdx.x, kc = blockIdx.y, b = blockIdx.z;
    int c0 = kc * 64;
    const float* Xg = X + ((size_t)b * 1024 + c0) * 256;
    for (int i = tid; i < 16384; i += 256) {
        int c = i >> 8, px = i & 255;
        int sy = px >> 4, sx = px & 15;
        int par = (sy & 1) * 2 + (sx & 1);
        sX[(c * 4 + par) * 64 + (sy >> 1) * 8 + (sx >> 1)] = Xg[i];
    }
    __syncthreads();
    int lane = tid & 63;
    int w = __builtin_amdgcn_readfirstlane(tid >> 6);
    int oh = lane >> 3, ow = lane & 7;
    int loff[9]; float lmsk[9];
#pragma unroll
    for (int kh = 0; kh < 3; ++kh)
#pragma unroll
        for (int kw = 0; kw < 3; ++kw) {
            int py = (kh == 1) ? 0 : 1;
            int pxp = (kw == 1) ? 0 : 1;
            int u = oh - ((kh == 0) ? 1 : 0);
            int v = ow - ((kw == 0) ? 1 : 0);
            float m = (u >= 0 && v >= 0) ? 1.f : 0.f;
            if (u < 0) u = 0;
            if (v < 0) v = 0;
            loff[kh * 3 + kw] = (py * 2 + pxp) * 64 + u * 8 + v;
            lmsk[kh * 3 + kw] = m;
        }
    float acc[16];
#pragma unroll
    for (int j = 0; j < 16; ++j) acc[j] = 0.f;
    const float* wb = WP + (size_t)ot * 589824 + (size_t)c0 * 576 + w * 16;
    for (int c = 0; c < 64; ++c) {
        const float* xb = sX + c * 256;
        const float* wc = wb + (size_t)c * 576;
#pragma unroll
        for (int tap = 0; tap < 9; ++tap) {
            float xv = xb[loff[tap]] * lmsk[tap];
            const float* wr = wc + tap * 64;
#pragma unroll
            for (int j = 0; j < 16; ++j) acc[j] = fmaf(xv, wr[j], acc[j]);
        }
    }
    float* pp = part + ((size_t)((kc * 2 + b) * 1024 + ot * 64 + w * 16)) * 64 + lane;
#pragma unroll
    for (int j = 0; j < 16; ++j) pp[(size_t)j * 64] = acc[j];
}

// ---- down-conv v2: K-split reduction + bias ----
__global__ __launch_bounds__(256) void k_downred(const float* __restrict__ part,
                                                 const float* __restrict__ bias,
                                                 float* __restrict__ out) {
    int idx = blockIdx.x * 256 + threadIdx.x;   // < 131072 == b*65536 + o*64 + px
    int o = (idx >> 6) & 1023;
    int b = idx >> 16;
    int px = idx & 63;
    float s = bias[o];
#pragma unroll
    for (int kcs = 0; kcs < 16; ++kcs)
        s += part[((size_t)(kcs * 2 + b) * 1024 + o) * 64 + px];
    out[idx] = s;
}

// fused concat -> bf16 CHANNELS-LAST (b, pos4096, ch2816)  [R5-proven 1-elem version]
__global__ void k_fusedcat_bf(const float* __restrict__ f0, const float* __restrict__ f1,
                              const float* __restrict__ f2, const float* __restrict__ f3,
                              short* __restrict__ out) {
    int idx = blockIdx.x * 256 + threadIdx.x;       // < 23068672
    int ch = idx % 2816;
    int t = idx / 2816;
    int pos = t & 4095;
    int b = t >> 12;
    float v;
    if (ch < 256) {
        v = f0[((size_t)(b * 256 + ch)) * 4096 + pos];
    } else {
        const float* src; int sh;
        if (ch < 768)       { src = f1 + ((size_t)(b * 512 + (ch - 256))) * 1024; sh = 32; }
        else if (ch < 1792) { src = f2 + ((size_t)(b * 1024 + (ch - 768))) * 256; sh = 16; }
        else                { src = f3 + ((size_t)(b * 1024 + (ch - 1792))) * 64; sh = 8;  }
        int y = pos >> 6, x = pos & 63;
        float r = (float)(sh - 1) / 63.0f;
        float cy = y * r, cx = x * r;
        int i0 = (int)cy; if (i0 > sh - 2) i0 = sh - 2;
        int j0 = (int)cx; if (j0 > sh - 2) j0 = sh - 2;
        float ty = cy - (float)i0, tx = cx - (float)j0;
        const float* s0 = src + i0 * sh + j0;
        float v00 = s0[0], v01 = s0[1], v10 = s0[sh], v11 = s0[sh + 1];
        float c0 = v00 + ty * (v10 - v00);
        float c1 = v01 + ty * (v11 - v01);
        v = c0 + tx * (c1 - c0);
    }
    out[idx] = f2bf(v);
}

// fuse weight prep: bf16 B-fragment order for 16x16x32 MFMA.
__global__ void k_wfuseprep(const float* __restrict__ w, short* __restrict__ wb) {
    int idx = blockIdx.x * 256 + threadIdx.x;       // < 720896
    int j = idx & 7;
    int lane = (idx >> 3) & 63;
    int ntile = (idx >> 9) & 15;
    int chunk = idx >> 13;                          // < 88
    int oc = ntile * 16 + (lane & 15);
    int c = chunk * 32 + (lane >> 4) * 8 + j;
    wb[idx] = f2bf(w[(size_t)oc * 2816 + c]);
}

// fuse GEMM on MFMA bf16: M=8192 px, N=256 oc, K=2816.
__global__ __launch_bounds__(256) void k_fuse_mfma(const short* __restrict__ A,
                                                   const bf16x8* __restrict__ WB,
                                                   const float* __restrict__ bias,
                                                   short* __restrict__ out) {
    int tid = threadIdx.x;
    int lane = tid & 63, w = tid >> 6;
    int row0 = blockIdx.x * 16;                     // global px row of tile
    int l15 = lane & 15, q = lane >> 4;
    int arow = row0 + l15;
    f32x4 acc[4];
#pragma unroll
    for (int nn = 0; nn < 4; ++nn) acc[nn] = (f32x4){0.f, 0.f, 0.f, 0.f};
    const short* arp = A + (size_t)arow * 2816 + q * 8;
    for (int chunk = 0; chunk < 88; ++chunk) {
        bf16x8 a = *(const bf16x8*)(arp + chunk * 32);
        const bf16x8* wbp = WB + ((size_t)(chunk * 16 + w * 4) * 64) + lane;
#pragma unroll
        for (int nn = 0; nn < 4; ++nn) {
            bf16x8 bf = wbp[nn * 64];
            acc[nn] = __builtin_amdgcn_mfma_f32_16x16x32_bf16(a, bf, acc[nn], 0, 0, 0);
        }
    }
#pragma unroll
    for (int nn = 0; nn < 4; ++nn) {
        int oc = (w * 4 + nn) * 16 + l15;
        float bs = bias[oc];
#pragma unroll
        for (int r = 0; r < 4; ++r) {
            int m = q * 4 + r;
            out[(size_t)(row0 + m) * 256 + oc] = f2bf(fmaxf(acc[nn][r] + bs, 0.f));
        }
    }
}

// bilinear 64->224 on bf16 channels-last, 8 ch per thread
__global__ void k_resize224bf2(const short* __restrict__ in, short* __restrict__ out) {
    int idx = blockIdx.x * 256 + threadIdx.x;       // < 3211264
    int c8 = (idx & 31) * 8;
    int p = idx >> 5;                               // < 100352
    int b = p / NP;
    int pos = p - b * NP;
    int y = pos / HW, x = pos - y * HW;
    const float r = (float)(63.0 / 223.0);
    float cy = y * r, cx = x * r;
    int i0 = (int)cy; if (i0 > 62) i0 = 62;
    int j0 = (int)cx; if (j0 > 62) j0 = 62;
    float ty = cy - (float)i0, tx = cx - (float)j0;
    const short* base = in + ((size_t)b * 4096) * 256 + c8;
    const bf16x8 v00 = *(const bf16x8*)(base + (size_t)(i0 * 64 + j0) * 256);
    const bf16x8 v01 = *(const bf16x8*)(base + (size_t)(i0 * 64 + j0 + 1) * 256);
    const bf16x8 v10 = *(const bf16x8*)(base + (size_t)((i0 + 1) * 64 + j0) * 256);
    const bf16x8 v11 = *(const bf16x8*)(base + (size_t)((i0 + 1) * 64 + j0 + 1) * 256);
    bf16x8 o;
#pragma unroll
    for (int k = 0; k < 8; ++k) {
        float a00 = bf2f(v00[k]), a01 = bf2f(v01[k]);
        float a10 = bf2f(v10[k]), a11 = bf2f(v11[k]);
        float c0 = a00 + ty * (a10 - a00);
        float c1 = a01 + ty * (a11 - a01);
        o[k] = f2bf(c0 + tx * (c1 - c0));
    }
    *(bf16x8*)(out + ((size_t)b * NP + pos) * 256 + c8) = o;
}

// conv1 weight prep: BN-fold + bf16 + MFMA B-fragment order.
__global__ void k_w1prep(const float* __restrict__ w, const float* __restrict__ bias,
                         const float* __restrict__ g, const float* __restrict__ bb,
                         const float* __restrict__ m, const float* __restrict__ v,
                         short* __restrict__ wb, float* __restrict__ shift) {
    int idx = blockIdx.x * 256 + threadIdx.x;      // < 294912
    int j = idx & 7;
    int lane = (idx >> 3) & 63;
    int nt = (idx >> 9) & 7;
    int tc = idx >> 12;
    int tap = tc % 9, chunk = tc / 9;
    int oc = nt * 16 + (lane & 15);
    int c = chunk * 32 + (lane >> 4) * 8 + j;
    float s = g[oc] * rsqrtf(v[oc] + 1e-5f);
    wb[idx] = f2bf(w[((size_t)oc * 256 + c) * 9 + tap] * s);
    if (idx < 128) {
        float si = g[idx] * rsqrtf(v[idx] + 1e-5f);
        shift[idx] = (bias[idx] - m[idx]) * si + bb[idx];
    }
}

// conv1 as implicit GEMM on MFMA bf16.
__global__ __launch_bounds__(256) void k_conv1mfma(const short* __restrict__ X,
                                                   const bf16x8* __restrict__ WB,
                                                   const float* __restrict__ shift,
                                                   float* __restrict__ out) {
    int tid = threadIdx.x;
    int lane = tid & 63, w = tid >> 6;
    int t = blockIdx.x;
    int b = blockIdx.y;
    int ty0 = (t / 28) * 16, tx0 = (t % 28) * 8;
    int l15 = lane & 15, q = lane >> 4;
    int loc0 = w * 32 + l15;
    int loc1 = loc0 + 16;
    int py0 = ty0 + (loc0 >> 3), px0 = tx0 + (loc0 & 7);
    int py1 = ty0 + (loc1 >> 3), px1 = tx0 + (loc1 & 7);
    int csub = q * 8;
    f32x4 acc0[8], acc1[8];
#pragma unroll
    for (int nt = 0; nt < 8; ++nt) {
        acc0[nt] = (f32x4){0.f, 0.f, 0.f, 0.f};
        acc1[nt] = (f32x4){0.f, 0.f, 0.f, 0.f};
    }
    const short* Xb = X + (size_t)b * NP * 256;
    const bf16x8 zv = {0, 0, 0, 0, 0, 0, 0, 0};
    for (int chunk = 0; chunk < 8; ++chunk) {
        int c0 = chunk * 32 + csub;
#pragma unroll
        for (int tap = 0; tap < 9; ++tap) {
            int dy = tap / 3 - 1, dx = tap % 3 - 1;
            int sy0 = py0 + dy, sx0 = px0 + dx;
            int sy1 = py1 + dy, sx1 = px1 + dx;
            bf16x8 a0 = zv, a1 = zv;
            if ((unsigned)sy0 < HW && (unsigned)sx0 < HW)
                a0 = *(const bf16x8*)(Xb + ((size_t)sy0 * HW + sx0) * 256 + c0);
            if ((unsigned)sy1 < HW && (unsigned)sx1 < HW)
                a1 = *(const bf16x8*)(Xb + ((size_t)sy1 * HW + sx1) * 256 + c0);
            const bf16x8* wbp = WB + (size_t)((chunk * 9 + tap) * 8) * 64 + lane;
#pragma unroll
            for (int nt = 0; nt < 8; ++nt) {
                bf16x8 bf = wbp[nt * 64];
                acc0[nt] = __builtin_amdgcn_mfma_f32_16x16x32_bf16(a0, bf, acc0[nt], 0, 0, 0);
                acc1[nt] = __builtin_amdgcn_mfma_f32_16x16x32_bf16(a1, bf, acc1[nt], 0, 0, 0);
            }
        }
    }
    int m0 = w * 32, m1 = w * 32 + 16;
#pragma unroll
    for (int nt = 0; nt < 8; ++nt) {
        int oc = nt * 16 + l15;
        float sh = shift[oc];
        float* ob = out + ((size_t)(b * 128 + oc)) * NP;
#pragma unroll
        for (int r = 0; r < 4; ++r) {
            int md = q * 4 + r;
            int lm = m0 + md;
            int py = ty0 + (lm >> 3), px = tx0 + (lm & 7);
            ob[py * HW + px] = fmaxf(acc0[nt][r] + sh, 0.f);
            lm = m1 + md;
            py = ty0 + (lm >> 3); px = tx0 + (lm & 7);
            ob[py * HW + px] = fmaxf(acc1[nt][r] + sh, 0.f);
        }
    }
}

// ---- conv3 v3: weight repack (O,C,3,3) -> WP[c][tap][o] ----
__global__ void k_wc3prep(const float* __restrict__ W, float* __restrict__ WP,
                          int C, int O) {
    int idx = blockIdx.x * 256 + threadIdx.x;
    if (idx >= C * 9 * O) return;
    int o = idx % O;
    int t = idx / O;
    int tap = t % 9, c = t / 9;
    WP[idx] = W[((size_t)o * C + c) * 9 + tap];
}

// ---- conv3 v3 main: K-split, all-O-per-block, 32x8 px tile ----
template <int O, int CB>
__global__ __launch_bounds__(256) void k_conv3v3(const float* __restrict__ in,
                                                 const float* __restrict__ WP,
                                                 float* __restrict__ part, int C) {
    __shared__ float sX[8 * 360];               // 8 ch x 10 rows x 36-stride
    int tid = threadIdx.x;
    int tb = blockIdx.x, s = blockIdx.y, b = blockIdx.z;
    int ty0 = (tb / 7) * 8, tx0 = (tb % 7) * 32;
    int px = tid & 31, py = tid >> 5;
    float acc[O];
#pragma unroll
    for (int o = 0; o < O; ++o) acc[o] = 0.f;
    int c0 = s * CB;
    const float* ic = in + ((size_t)b * C + c0) * NP;
    const float* wbase = WP + (size_t)c0 * 9 * O;
    for (int cc = 0; cc < CB; cc += 8) {
        __syncthreads();
        for (int i = tid; i < 8 * 340; i += 256) {
            int c = i / 340;
            int r = i - c * 340;
            int y = r / 34, x = r - y * 34;
            int sy = ty0 + y - 1, sx = tx0 + x - 1;
            float v = 0.f;
            if ((unsigned)sy < HW && (unsigned)sx < HW)
                v = ic[(size_t)(cc + c) * NP + sy * HW + sx];
            sX[c * 360 + y * 36 + x] = v;
        }
        __syncthreads();
        const float* xb = sX + py * 36 + px;
#pragma unroll 1
        for (int c = 0; c < 8; ++c) {
            const float* xc = xb + c * 360;
            const float* wc = wbase + (size_t)(cc + c) * 9 * O;
#pragma unroll
            for (int kh = 0; kh < 3; ++kh)
#pragma unroll
                for (int kw = 0; kw < 3; ++kw) {
                    float xv = xc[kh * 36 + kw];
                    const float* wt = wc + (kh * 3 + kw) * O;
#pragma unroll
                    for (int o = 0; o < O; ++o) acc[o] = fmaf(xv, wt[o], acc[o]);
                }
        }
    }
    int gy = ty0 + py, gx = tx0 + px;
    float* ob = part + ((size_t)(s * BATCH + b) * O) * NP + (size_t)gy * HW + gx;
#pragma unroll
    for (int o = 0; o < O; ++o) ob[(size_t)o * NP] = acc[o];
}

// ---- fused conv2 reduce + bias + sim (prototypes dot) ----
// thread = (b,pos): reduce 4 K-split partials per o -> pe (write), then 64 proto dots.
__global__ __launch_bounds__(256) void k_red32sim(const float* __restrict__ part,
                                                  const float* __restrict__ bias,
                                                  const float* __restrict__ proto,
                                                  float* __restrict__ o_pe,
                                                  float* __restrict__ simout) {
    int idx = blockIdx.x * 256 + threadIdx.x;   // < B*NP
    int b = idx / NP, pos = idx - b * NP;
    float v[32];
#pragma unroll
    for (int o = 0; o < 32; ++o) {
        float s = bias[o];
#pragma unroll
        for (int s2 = 0; s2 < 4; ++s2)
            s += part[((size_t)((s2 * BATCH + b) * 32 + o)) * NP + pos];
        v[o] = s;
        o_pe[((size_t)(b * 32 + o)) * NP + pos] = s;
    }
    const float scale = 1.0f / sqrtf(32.0f);
    float* so = simout + (size_t)b * NPROTO * NP + pos;
    for (int q = 0; q < NPROTO; ++q) {
        float acc = 0.f;
#pragma unroll
        for (int e = 0; e < 32; ++e) acc = fmaf(v[e], proto[q * EMBD + e], acc);
        so[(size_t)q * NP] = acc * scale;
    }
}

__global__ void k_init(float* acc) { if (threadIdx.x < 8) acc[threadIdx.x] = 0.f; }

__device__ __forceinline__ float block_reduce_sum(float v) {
    __shared__ float sh[4];
#pragma unroll
    for (int off = 32; off > 0; off >>= 1) v += __shfl_down(v, off);
    int lane = threadIdx.x & 63, wv = threadIdx.x >> 6;
    if (lane == 0) sh[wv] = v;
    __syncthreads();
    return (threadIdx.x == 0) ? (sh[0] + sh[1] + sh[2] + sh[3]) : 0.f;
}

__global__ __launch_bounds__(256) void k_edge(const float* __restrict__ pe,
                                              float* __restrict__ edge,
                                              float* __restrict__ acc) {
    int idx = blockIdx.x * 256 + threadIdx.x;
    int b = idx / NP, pos = idx - b * NP;
    int h = pos / HW, w = pos - h * HW;
    int wn = (w < HW - 1) ? w : HW - 2;
    int hn = (h < HW - 1) ? h : HW - 2;
    const float* pb = pe + (size_t)b * EMBD * NP;
    float sx = 0.f, sy = 0.f;
#pragma unroll 4
    for (int e = 0; e < EMBD; ++e) {
        const float* p = pb + (size_t)e * NP;
        sx += fabsf(p[h * HW + wn] - p[h * HW + wn + 1]);
        sy += fabsf(p[hn * HW + w] - p[hn * HW + HW + w]);
    }
    float ev = (sx + sy) * (0.5f / 32.0f);
    edge[idx] = ev;
    float tot = block_reduce_sum(ev);
    if (threadIdx.x == 0) atomicAdd(acc, tot);
}

// ---- fused 2-pass edge-aware smoothing (LDS-tiled, 16x16 out-tile) ----
// in: raw sim; out: twice-smoothed sim (different buffer -> no cross-block race).
__global__ __launch_bounds__(256) void k_smooth2x(const float* __restrict__ sin_,
                                                  const float* __restrict__ edge,
                                                  const float* __restrict__ acc,
                                                  float* __restrict__ sout) {
    __shared__ float sIn[20 * 20];      // origin (oy0-2, ox0-2)
    __shared__ float sE[18 * 18];       // edge at origin (oy0-1, ox0-1)
    __shared__ float s1[18 * 18];       // pass-1 result, origin (oy0-1, ox0-1)
    int tid = threadIdx.x;
    int tile = blockIdx.x, p = blockIdx.y, b = blockIdx.z;
    int oy0 = (tile / 14) * 16, ox0 = (tile % 14) * 16;
    float mean = acc[0] * (1.0f / 100352.0f);
    const float* sc = sin_ + ((size_t)(b * NPROTO + p)) * NP;
    const float* eb = edge + (size_t)b * NP;
    for (int i = tid; i < 400; i += 256) {
        int y = i / 20, x = i - y * 20;
        int gy = oy0 - 2 + y, gx = ox0 - 2 + x;
        float v = 0.f;
        if ((unsigned)gy < HW && (unsigned)gx < HW) v = sc[gy * HW + gx];
        sIn[i] = v;
    }
    for (int i = tid; i < 324; i += 256) {
        int y = i / 18, x = i - y * 18;
        int gy = oy0 - 1 + y, gx = ox0 - 1 + x;
        float e = 0.f;
        if ((unsigned)gy < HW && (unsigned)gx < HW) e = eb[gy * HW + gx];
        sE[i] = e;
    }
    __syncthreads();
    // pass 1 over 18x18 (zero for out-of-image px)
    for (int i = tid; i < 324; i += 256) {
        int y = i / 18, x = i - y * 18;
        int gy = oy0 - 1 + y, gx = ox0 - 1 + x;
        float r = 0.f;
        if ((unsigned)gy < HW && (unsigned)gx < HW) {
            const float* c0 = sIn + (y + 1) * 20 + (x + 1);
            float s = c0[-21] + c0[-20] + c0[-19]
                    + c0[-1]  + c0[0]   + c0[1]
                    + c0[19]  + c0[20]  + c0[21];
            float m = (sE[i] > mean) ? 1.f : 0.f;
            r = m * c0[0] + (1.f - m) * (s * (1.0f / 9.0f));
        }
        s1[i] = r;
    }
    __syncthreads();
    // pass 2 over 16x16 (all in-image)
    {
        int px = tid & 15, py = tid >> 4;
        int gy = oy0 + py, gx = ox0 + px;
        const float* c1 = s1 + (py + 1) * 18 + (px + 1);
        float s = c1[-19] + c1[-18] + c1[-17]
                + c1[-1]  + c1[0]   + c1[1]
                + c1[17]  + c1[18]  + c1[19];
        float m = (sE[(py + 1) * 18 + (px + 1)] > mean) ? 1.f : 0.f;
        sout[((size_t)(b * NPROTO + p)) * NP + (size_t)gy * HW + gx] =
            m * c1[0] + (1.f - m) * (s * (1.0f / 9.0f));
    }
}

__global__ __launch_bounds__(256) void k_entropy(const float* __restrict__ sim,
                                                 float* __restrict__ acc) {
    int idx = blockIdx.x * 256 + threadIdx.x;
    int b = idx / NP, pos = idx - b * NP;
    const float* s = sim + (size_t)b * NPROTO * NP + pos;
    float v[NPROTO];
    float mx = -3.0e38f;
#pragma unroll
    for (int q = 0; q < NPROTO; ++q) { v[q] = s[(size_t)q * NP]; mx = fmaxf(mx, v[q]); }
    float sum = 0.f;
#pragma unroll
    for (int q = 0; q < NPROTO; ++q) { float e = expf(v[q] - mx); v[q] = e; sum += e; }
    float inv = 1.f / sum;
    float ent = 0.f;
#pragma unroll
    for (int q = 0; q < NPROTO; ++q) {
        float a = v[q] * inv;
        ent -= a * logf(a + 1e-8f);
    }
    float tot = block_reduce_sum(ent);
    if (threadIdx.x == 0) atomicAdd(acc + 1, tot);
}

__global__ void k_bb(const float* __restrict__ pb, const float* __restrict__ bs,
                     float* __restrict__ bbuf, float* __restrict__ obb) {
    int t = threadIdx.x;
    if (t < NPROTO) {
        float v = 1.f + tanhf(pb[t]) * bs[0];
        bbuf[t] = v;
        obb[t] = v;
        obb[NPROTO + t] = v;
    }
}

// ---- fused smooth-conv reduce + bias + softmax + act + bgain ----
__global__ __launch_bounds__(256) void k_actsm2(const float* __restrict__ part,
                                                const float* __restrict__ bias,
                                                const float* __restrict__ bb,
                                                float* __restrict__ act,
                                                float* __restrict__ bgain) {
    int idx = blockIdx.x * 256 + threadIdx.x;
    int b = idx / NP, pos = idx - b * NP;
    float v[NPROTO];
    float mx = -3.0e38f;
#pragma unroll
    for (int q = 0; q < NPROTO; ++q) {
        float s = bias[q];
        s += part[((size_t)((0 * BATCH + b) * NPROTO + q)) * NP + pos];
        s += part[((size_t)((1 * BATCH + b) * NPROTO + q)) * NP + pos];
        v[q] = s;
        mx = fmaxf(mx, s);
    }
    float sum = 0.f;
#pragma unroll
    for (int q = 0; q < NPROTO; ++q) { float e = expf(v[q] - mx); v[q] = e; sum += e; }
    float inv = 1.f / sum;
    float* a = act + (size_t)b * NPROTO * NP + pos;
    float bg = 0.f;
#pragma unroll
    for (int q = 0; q < NPROTO; ++q) {
        float p = v[q] * inv;
        a[(size_t)q * NP] = p;
        bg = fmaf(p, bb[q], bg);
    }
    bgain[idx] = bg;
}

__global__ void k_headprep(const float* __restrict__ w1, const float* __restrict__ b1,
                           const float* __restrict__ g1, const float* __restrict__ be1,
                           const float* __restrict__ m1, const float* __restrict__ v1,
                           const float* __restrict__ w2, const float* __restrict__ b2,
                           const float* __restrict__ g2, const float* __restrict__ be2,
                           const float* __restrict__ m2, const float* __restrict__ v2,
                           float* __restrict__ wf) {
    int oc = blockIdx.x * 256 + threadIdx.x;
    if (oc >= 512) return;
    float s1 = g1[oc] * rsqrtf(v1[oc] + 1e-5f);
#pragma unroll
    for (int k = 0; k < 9; ++k) wf[oc * 9 + k] = w1[oc * 9 + k] * s1;
    wf[41472 + oc] = (b1[oc] - m1[oc]) * s1 + be1[oc];
    float s2 = g2[oc] * rsqrtf(v2[oc] + 1e-5f);
    int g = oc >> 3, j = oc & 7;
#pragma unroll
    for (int icc = 0; icc < 8; ++icc)
#pragma unroll
        for (int k = 0; k < 9; ++k)
            wf[4608 + (size_t)g * 576 + icc * 72 + j * 9 + k] = w2[((size_t)oc * 8 + icc) * 9 + k] * s2;
    wf[41984 + oc] = (b2[oc] - m2[oc]) * s2 + be2[oc];
}

// fused 3-layer grouped heads, 16x16 out-tile (R4 verified version).
__global__ __launch_bounds__(256) void k_heads(
    const float* __restrict__ act, const float* __restrict__ wf,
    const float* __restrict__ w3, const float* __restrict__ b3,
    float* __restrict__ res) {
    __shared__ float sA[22 * 24];           // origin (oy0-3, ox0-3), stride 24
    __shared__ float sH1[8][20 * 22];       // origin (oy0-2, ox0-2), stride 22
    __shared__ float sH2[8][18 * 18];       // origin (oy0-1, ox0-1), stride 18
    int tid = threadIdx.x;
    int tile = blockIdx.x, g = blockIdx.y, b = blockIdx.z;
    int oy0 = (tile / 14) * 16, ox0 = (tile % 14) * 16;
    const float* ain = act + (size_t)(b * NPROTO + g) * NP;

    for (int i = tid; i < 484; i += 256) {
        int y = i / 22, x = i - y * 22;
        int gy = oy0 - 3 + y, gx = ox0 - 3 + x;
        float v = 0.f;
        if ((unsigned)gy < HW && (unsigned)gx < HW) v = ain[gy * HW + gx];
        sA[y * 24 + x] = v;
    }
    __syncthreads();

    // stage1: 20x20, 1 px/thread
    const float* b1f = wf + 41472 + g * 8;
    for (int i = tid; i < 400; i += 256) {
        int y = i / 20, x = i - y * 20;
        int gy = oy0 - 2 + y, gx = ox0 - 2 + x;
        float keep = ((unsigned)gy < HW && (unsigned)gx < HW) ? 1.f : 0.f;
        const float* s0 = sA + y * 24 + x;
        float r0 = s0[0],  r1 = s0[1],  r2 = s0[2];
        float r3 = s0[24], r4 = s0[25], r5 = s0[26];
        float r6 = s0[48], r7 = s0[49], r8 = s0[50];
#pragma unroll
        for (int j = 0; j < 8; ++j) {
            const float* w = wf + (g * 8 + j) * 9;
            float v = fmaf(r0, w[0], fmaf(r1, w[1], fmaf(r2, w[2],
                      fmaf(r3, w[3], fmaf(r4, w[4], fmaf(r5, w[5],
                      fmaf(r6, w[6], fmaf(r7, w[7], fmaf(r8, w[8], b1f[j])))))))));
            sH1[j][y * 22 + x] = fmaxf(v, 0.f) * keep;
        }
    }
    __syncthreads();

    // stage2: 18x18 as 18x9 pixel pairs, f32x2 packed
    const float* w2f = wf + 4608 + (size_t)g * 576;
    const float* b2f = wf + 41984 + g * 8;
    if (tid < 162) {
        int y2 = tid / 9, xp = (tid - y2 * 9) * 2;
        f32x2 a2[8];
#pragma unroll
        for (int j = 0; j < 8; ++j) { float bv = b2f[j]; a2[j] = (f32x2){bv, bv}; }
#pragma unroll
        for (int icc = 0; icc < 8; ++icc) {
            const float* s0 = &sH1[icc][y2 * 22 + xp];
            f32x2 t[9];
#pragma unroll
            for (int r = 0; r < 3; ++r) {
                float f0 = s0[r * 22], f1 = s0[r * 22 + 1];
                float f2 = s0[r * 22 + 2], f3 = s0[r * 22 + 3];
                t[r * 3 + 0] = (f32x2){f0, f1};
                t[r * 3 + 1] = (f32x2){f1, f2};
                t[r * 3 + 2] = (f32x2){f2, f3};
            }
            const float* wr = w2f + icc * 72;
#pragma unroll
            for (int j = 0; j < 8; ++j) {
                const float* wj = wr + j * 9;
#pragma unroll
                for (int k = 0; k < 9; ++k) {
                    float wv = wj[k];
                    a2[j] = __builtin_elementwise_fma(t[k], (f32x2){wv, wv}, a2[j]);
                }
            }
        }
        int gy = oy0 - 1 + y2;
        int gx0 = ox0 - 1 + xp;
        float k0 = ((unsigned)gy < HW && (unsigned)gx0 < HW) ? 1.f : 0.f;
        float k1 = ((unsigned)gy < HW && (unsigned)(gx0 + 1) < HW) ? 1.f : 0.f;
        f32x2 kp = (f32x2){k0, k1};
        const f32x2 z2 = (f32x2){0.f, 0.f};
#pragma unroll
        for (int j = 0; j < 8; ++j) {
            f32x2 v = __builtin_elementwise_max(a2[j], z2) * kp;
            sH2[j][y2 * 18 + xp] = v.x;
            sH2[j][y2 * 18 + xp + 1] = v.y;
        }
    }
    __syncthreads();

    // stage3: 16x16 as 16x8 pairs, f32x2 packed
    if (tid < 128) {
        int y3 = tid >> 3, xp = (tid & 7) * 2;
        float bv = b3[g];
        f32x2 a2 = (f32x2){bv, bv};
#pragma unroll
        for (int icc = 0; icc < 8; ++icc) {
            const float* s0 = &sH2[icc][y3 * 18 + xp];
            const float* w = w3 + (size_t)(g * 8 + icc) * 9;
#pragma unroll
            for (int r = 0; r < 3; ++r) {
                float f0 = s0[r * 18], f1 = s0[r * 18 + 1];
                float f2 = s0[r * 18 + 2], f3 = s0[r * 18 + 3];
                float w0 = w[r * 3], w1 = w[r * 3 + 1], w2v = w[r * 3 + 2];
                a2 = __builtin_elementwise_fma((f32x2){f0, f1}, (f32x2){w0, w0}, a2);
                a2 = __builtin_elementwise_fma((f32x2){f1, f2}, (f32x2){w1, w1}, a2);
                a2 = __builtin_elementwise_fma((f32x2){f2, f3}, (f32x2){w2v, w2v}, a2);
            }
        }
        float* rp = res + (size_t)(b * NPROTO + g) * NP + (size_t)(oy0 + y3) * HW + (ox0 + xp);
        rp[0] = a2.x;
        rp[1] = a2.y;
    }
}

__global__ __launch_bounds__(256) void k_final(const float* __restrict__ act,
                                               const float* __restrict__ res,
                                               const float* __restrict__ bgain,
                                               const float* __restrict__ rscale,
                                               float* __restrict__ owt,
                                               float* __restrict__ oibm) {
    int idx = blockIdx.x * 256 + threadIdx.x;
    int b = idx / NP, pos = idx - b * NP;
    const float* a = act + (size_t)b * NPROTO * NP + pos;
    const float* r = res + (size_t)b * NPROTO * NP + pos;
    float wt = 0.f;
#pragma unroll
    for (int q = 0; q < NPROTO; ++q) wt = fmaf(a[(size_t)q * NP], r[(size_t)q * NP], wt);
    owt[idx] = wt;
    float gn = bgain[idx] * (1.f + tanhf(wt) * rscale[0]);
    gn = fminf(fmaxf(gn, 0.5f), 2.0f);
    oibm[idx] = gn;
}

__global__ void k_entfinal(const float* __restrict__ acc, float* __restrict__ o) {
    if (threadIdx.x == 0) o[0] = acc[1] * (1.0f / 100352.0f);
}

// ======================================================================
extern "C" void kernel_launch(void* const* d_in, const int* in_sizes, int n_in,
                              void* d_out, int out_size, void* d_ws, size_t ws_size,
                              hipStream_t stream) {
    const float* tokens[4] = {(const float*)d_in[0], (const float*)d_in[1],
                              (const float*)d_in[2], (const float*)d_in[3]};
    const float* proj_w[4] = {(const float*)d_in[4], (const float*)d_in[6],
                              (const float*)d_in[8], (const float*)d_in[10]};
    const float* proj_b[4] = {(const float*)d_in[5], (const float*)d_in[7],
                              (const float*)d_in[9], (const float*)d_in[11]};
    const float* up_w0 = (const float*)d_in[12]; const float* up_b0 = (const float*)d_in[13];
    const float* up_w1 = (const float*)d_in[14]; const float* up_b1 = (const float*)d_in[15];
    const float* down_w3 = (const float*)d_in[16]; const float* down_b3 = (const float*)d_in[17];
    const float* fuse_w = (const float*)d_in[18]; const float* fuse_b = (const float*)d_in[19];
    const float* pe_w1 = (const float*)d_in[20]; const float* pe_b1 = (const float*)d_in[21];
    const float* pe_bn_g = (const float*)d_in[22]; const float* pe_bn_b = (const float*)d_in[23];
    const float* pe_bn_m = (const float*)d_in[24]; const float* pe_bn_v = (const float*)d_in[25];
    const float* pe_w2 = (const float*)d_in[26]; const float* pe_b2 = (const float*)d_in[27];
    const float* prototypes = (const float*)d_in[28];
    const float* proto_biases = (const float*)d_in[29];
    const float* bias_scale = (const float*)d_in[30];
    const float* smooth_w = (const float*)d_in[31]; const float* smooth_b = (const float*)d_in[32];
    const float* hw1 = (const float*)d_in[33]; const float* hb1 = (const float*)d_in[34];
    const float* hg1 = (const float*)d_in[35]; const float* hbe1 = (const float*)d_in[36];
    const float* hm1 = (const float*)d_in[37]; const float* hv1 = (const float*)d_in[38];
    const float* hw2 = (const float*)d_in[39]; const float* hb2 = (const float*)d_in[40];
    const float* hg2 = (const float*)d_in[41]; const float* hbe2 = (const float*)d_in[42];
    const float* hm2 = (const float*)d_in[43]; const float* hv2 = (const float*)d_in[44];
    const float* hw3 = (const float*)d_in[45]; const float* hb3 = (const float*)d_in[46];
    const float* rscale = (const float*)d_in[47];
    (void)in_sizes; (void)n_in; (void)out_size; (void)ws_size;

    float* ws = (float*)d_ws;
    float* FEATS[4] = {ws + OFF_FEATS0, ws + OFF_FEATS1, ws + OFF_FEATS2, ws + OFF_FEATS3};
    float* TOKT = ws + OFF_TOKT;
    float* F0 = ws + OFF_F0; float* F1 = ws + OFF_F1; float* F3 = ws + OFF_F3;
    short* FUSEDBF = (short*)(ws + OFF_FUSEDBF);
    short* P64C = (short*)(ws + OFF_P64C);
    short* P224C = (short*)(ws + OFF_P224C);
    short* WB = (short*)(ws + OFF_WB);
    short* WFUSE = (short*)(ws + OFF_WFUSE);
    float* SHIFT = ws + OFF_SHIFT;
    float* T1 = ws + OFF_T1;
    float* SIMA = ws + OFF_SIMA;
    float* SIMRAW = ws + OFF_SIMRAW;
    float* EDGE = ws + OFF_EDGE; float* RES = ws + OFF_RES;
    float* BGAIN = ws + OFF_BGAIN; float* BBUF = ws + OFF_BB; float* ACC = ws + OFF_ACC;
    float* WF = ws + OFF_WF;
    float* WDP = ws + OFF_WD;
    float* PART = ws + OFF_PART;
    float* WCV0 = ws + OFF_WCV0;
    float* WCV1 = ws + OFF_WCV1;
    float* WC2 = ws + OFF_WC2;
    float* WSM = ws + OFF_WSM;
    float* PC2 = ws + OFF_PC2;      // conv2 partials (dead-P224C window)
    float* PSM = ws + OFF_PSM;      // smooth partials (dead-T1/SIMRAW window)

    float* out = (float*)d_out;
    float* o_ibm = out + O_IBM; float* o_act = out + O_ACT; float* o_bb = out + O_BB;
    float* o_wt = out + O_WT; float* o_pe = out + O_PE; float* o_ent = out + O_ENT;

    const int OCH[4] = {256, 512, 1024, 1024};
    for (int s = 0; s < 4; ++s)
        k_transpose<<<768, 256, 0, stream>>>(tokens[s], TOKT + s * 196608);
    for (int s = 0; s < 4; ++s)
        k_proj<<<dim3(OCH[s], BATCH), 256, 0, stream>>>(TOKT + s * 196608, proj_w[s], proj_b[s],
                                                        FEATS[s], OCH[s]);
    // convT v2: pack W (C x M tiled transpose), then LDS-GEMM
    k_wcvprep<16><<<dim3(8, 128), 256, 0, stream>>>(up_w0, WCV0, 256, 4096);
    k_wcvprep<8><<<dim3(16, 64), 256, 0, stream>>>(up_w1, WCV1, 512, 2048);
    k_convt2<16, 64, 4><<<dim3(256, BATCH), 256, 0, stream>>>(FEATS[0], WCV0, up_b0, F0, 256, 256);
    k_convt2<8, 64, 2><<<dim3(256, BATCH), 256, 0, stream>>>(FEATS[1], WCV1, up_b1, F1, 512, 512);
    // down-conv v2: pack W, K-split GEMM, reduce (+bias)
    k_wdprep<<<dim3(288, 32), 256, 0, stream>>>(down_w3, WDP);
    k_down2<<<dim3(16, 16, BATCH), 256, 0, stream>>>(FEATS[3], WDP, PART);
    k_downred<<<512, 256, 0, stream>>>(PART, down_b3, F3);
    // conv3 v3 weight packs (early, independent)
    k_wc3prep<<<144, 256, 0, stream>>>(pe_w2, WC2, 128, 32);
    k_wc3prep<<<144, 256, 0, stream>>>(smooth_w, WSM, 64, 64);
    k_wfuseprep<<<2816, 256, 0, stream>>>(fuse_w, WFUSE);
    k_fusedcat_bf<<<90112, 256, 0, stream>>>(F0, F1, FEATS[2], F3, FUSEDBF);
    k_fuse_mfma<<<512, 256, 0, stream>>>(FUSEDBF, (const bf16x8*)WFUSE, fuse_b, P64C);
    // FUSEDBF dead: WB/SHIFT (inside its range) safe now
    k_w1prep<<<1152, 256, 0, stream>>>(pe_w1, pe_b1, pe_bn_g, pe_bn_b, pe_bn_m, pe_bn_v,
                                       WB, SHIFT);
    k_resize224bf2<<<12544, 256, 0, stream>>>(P64C, P224C);
    k_conv1mfma<<<dim3(392, BATCH), 256, 0, stream>>>(P224C, (const bf16x8*)WB, SHIFT, T1);
    // conv2: K-split 4 (P224C dead -> PC2 window free)
    k_conv3v3<32, 32><<<dim3(196, 4, BATCH), 256, 0, stream>>>(T1, WC2, PC2, 128);
    // fused reduce+sim: raw sim -> SIMRAW (dead-T1 window; T1 consumed above)
    k_red32sim<<<392, 256, 0, stream>>>(PC2, pe_b2, prototypes, o_pe, SIMRAW);
    k_init<<<1, 64, 0, stream>>>(ACC);
    k_edge<<<392, 256, 0, stream>>>(o_pe, EDGE, ACC);
    // fused 2-pass smoothing: SIMRAW -> SIMA (PC2 dead; disjoint buffers, no race)
    k_smooth2x<<<dim3(196, NPROTO, BATCH), 256, 0, stream>>>(SIMRAW, EDGE, ACC, SIMA);
    k_entropy<<<392, 256, 0, stream>>>(SIMA, ACC);
    // smooth conv: K-split 2 (SIMRAW dead -> PSM window free)
    k_conv3v3<64, 32><<<dim3(196, 2, BATCH), 256, 0, stream>>>(SIMA, WSM, PSM, 64);
    k_bb<<<1, 64, 0, stream>>>(proto_biases, bias_scale, BBUF, o_bb);
    // fused reduce+softmax+act+bgain
    k_actsm2<<<392, 256, 0, stream>>>(PSM, smooth_b, BBUF, o_act, BGAIN);
    k_headprep<<<2, 256, 0, stream>>>(hw1, hb1, hg1, hbe1, hm1, hv1,
                                      hw2, hb2, hg2, hbe2, hm2, hv2, WF);
    k_heads<<<dim3(196, 64, BATCH), 256, 0, stream>>>(o_act, WF, hw3, hb3, RES);
    k_final<<<392, 256, 0, stream>>>(o_act, RES, BGAIN, rscale, o_wt, o_ibm);
    k_entfinal<<<1, 1, 0, stream>>>(ACC, o_ent);
}

// Round 10
// 1526.226 us; speedup vs baseline: 1.0490x; 1.0053x over previous
//
#include <hip/hip_runtime.h>
#include <math.h>

// ---------------- problem constants ----------------
#define BATCH 2
#define NTOK 256
#define INCH 384
#define NP 50176          // 224*224
#define HW 224
#define NPROTO 64
#define EMBD 32

// ---------------- workspace layout (floats) ----------------
#define OFF_FEATS0   0u
#define OFF_FEATS1   131072u
#define OFF_FEATS2   393216u
#define OFF_FEATS3   917504u
#define OFF_TOKT     1441792u
#define OFF_F0       2228224u
#define OFF_F1       4325376u
#define OFF_F3       5373952u
#define OFF_FUSEDBF  5505024u      // (2,4096,2816) bf16 = 11.53M fl -> ends 17.04M
#define OFF_WD       5505024u      // down-conv packed weights (9.44M fl) — dead-FUSEDBF window
#define OFF_PART     14942208u     // down-conv K-split partials (2.10M fl) -> ends 17039360
#define OFF_P64C     28573696u     // (2,4096,256) bf16 channels-last
#define OFF_P224C    0u            // (2,224,224,256) bf16 = 12.85M fl
#define OFF_T1       25690112u     // (2,128,224,224) fp32
#define OFF_PC2      0u            // conv2 K-split partials (4x2x32xNP = 12.85M fl, dead-P224C window)
#define OFF_SIMRAW   25690112u     // raw sim (2x64xNP = 6.42M fl, dead-T1 window)
#define OFF_PSM      25690112u     // smooth-conv K-split partials (2x2x64xNP, dead after SIMRAW consumed)
#define OFF_SIMA     0u
#define OFF_EDGE     12845056u
#define OFF_RES      13000000u
#define OFF_WB       13000000u     // conv1 MFMA weight frags (dead-RES window, written after fuse)
#define OFF_SHIFT    13200000u
#define OFF_BGAIN    19422528u
#define OFF_BB       19522880u
#define OFF_ACC      19523008u
#define OFF_WF       19523072u     // folded head weights (42496 fl)
#define OFF_WFUSE    20000000u     // fuse MFMA weight frags: 720896 bf16 = 360448 fl
#define OFF_WCV0     20500000u     // convT F0 packed W: 1048576 fl
#define OFF_WCV1     21600000u     // convT F1 packed W: 1048576 fl -> ends 22.65M
#define OFF_WC2      22700000u     // conv2 packed W [c][tap][o]: 36864 fl
#define OFF_WSM      22750000u     // smooth packed W [c][tap][o]: 36864 fl -> ends 22.79M (< T1 @25.69M)

// ---------------- output layout ----------------
#define O_IBM 0u
#define O_ACT 100352u
#define O_BB  6522880u
#define O_WT  6523008u
#define O_PE  6623360u
#define O_ENT 9834624u

typedef __attribute__((ext_vector_type(8))) short bf16x8;
typedef __attribute__((ext_vector_type(4))) float f32x4;
typedef __attribute__((ext_vector_type(2))) float f32x2;

__device__ __forceinline__ short f2bf(float f) {
    unsigned u = __float_as_uint(f);
    unsigned r = (u + 0x7fffu + ((u >> 16) & 1u)) >> 16;
    return (short)r;
}
__device__ __forceinline__ float bf2f(short s) {
    return __uint_as_float(((unsigned)(unsigned short)s) << 16);
}

// ======================================================================
__global__ void k_transpose(const float* __restrict__ in, float* __restrict__ out) {
    int idx = blockIdx.x * 256 + threadIdx.x;
    int n = idx & 255;
    int c = (idx >> 8) % INCH;
    int b = idx / (INCH * NTOK);
    out[idx] = in[(size_t)b * INCH * NTOK + (size_t)n * INCH + c];
}

__global__ __launch_bounds__(256) void k_proj(const float* __restrict__ A,
                                              const float* __restrict__ W,
                                              const float* __restrict__ bias,
                                              float* __restrict__ out, int O) {
    int p = threadIdx.x;
    int o = blockIdx.x, b = blockIdx.y;
    const float* a = A + (size_t)b * INCH * NTOK + p;
    const float* w = W + (size_t)o * INCH;
    float acc = bias[o];
    for (int c = 0; c < INCH; ++c) acc = fmaf(a[(size_t)c * NTOK], w[c], acc);
    out[((size_t)b * O + o) * NTOK + p] = acc;
}

// ---- convT v2: W repack (tiled transpose) ----
template <int NT>
__global__ __launch_bounds__(256) void k_wcvprep(const float* __restrict__ W,
                                                 float* __restrict__ WP, int C, int M) {
    __shared__ float t[32][33];
    int c0 = blockIdx.x * 32, m0 = blockIdx.y * 32;
    int tx = threadIdx.x & 31, ty = threadIdx.x >> 5;
#pragma unroll
    for (int r = 0; r < 4; ++r) {
        int cl = ty + r * 8;
        t[cl][tx] = W[(size_t)(c0 + cl) * M + m0 + tx];
    }
    __syncthreads();
    for (int i = threadIdx.x; i < 1024; i += 256) {
        int ml = i % NT;
        int tmp = i / NT;
        int cl = tmp & 31;
        int mh = tmp >> 5;
        WP[(size_t)(m0 / NT + mh) * C * NT + (size_t)(c0 + cl) * NT + ml] = t[cl][mh * NT + ml];
    }
}

// ---- convT v2 main: X-stationary LDS GEMM ----
template <int NT, int CCH, int K>
__global__ __launch_bounds__(256) void k_convt2(const float* __restrict__ X,
                                                const float* __restrict__ WP,
                                                const float* __restrict__ bias,
                                                float* __restrict__ out,
                                                int C, int O) {
    __shared__ float sX[CCH * 256];
    int tid = threadIdx.x;
    int nt = blockIdx.x, b = blockIdx.y;
    float acc[NT];
#pragma unroll
    for (int j = 0; j < NT; ++j) acc[j] = 0.f;
    const float* Xb = X + (size_t)b * C * 256;
    for (int cc = 0; cc < C; cc += CCH) {
        __syncthreads();
        const f32x4* Xg4 = (const f32x4*)(Xb + (size_t)cc * 256);
        f32x4* s4 = (f32x4*)sX;
        for (int i = tid; i < CCH * 64; i += 256) s4[i] = Xg4[i];
        __syncthreads();
        const float* wr = WP + ((size_t)nt * C + cc) * NT;
        for (int c = 0; c < CCH; ++c) {
            float xv = sX[c * 256 + tid];
            const float* w = wr + c * NT;
#pragma unroll
            for (int j = 0; j < NT; ++j) acc[j] = fmaf(xv, w[j], acc[j]);
        }
    }
    int h = tid >> 4, w = tid & 15;
    int S = 16 * K;
#pragma unroll
    for (int j = 0; j < NT; ++j) {
        int m = nt * NT + j;
        int o = m / (K * K);
        int ij = m - o * (K * K);
        int ii = ij / K, jj = ij - ii * K;
        out[((size_t)b * O + o) * (size_t)(S * S) + (h * K + ii) * S + (w * K + jj)] =
            acc[j] + bias[o];
    }
}

// ---- down-conv v2: W repack (tiled transpose) ----
__global__ __launch_bounds__(256) void k_wdprep(const float* __restrict__ W,
                                                float* __restrict__ WP) {
    __shared__ float t[32][33];
    int k0 = blockIdx.x * 32, o0 = blockIdx.y * 32;
    int tx = threadIdx.x & 31, ty = threadIdx.x >> 5;
#pragma unroll
    for (int r = 0; r < 4; ++r) {
        int orow = ty + r * 8;
        t[orow][tx] = W[(size_t)(o0 + orow) * 9216 + k0 + tx];
    }
    __syncthreads();
#pragma unroll
    for (int r = 0; r < 4; ++r) {
        int krow = ty + r * 8;
        int o = o0 + tx;
        WP[(size_t)(o >> 6) * 589824 + (size_t)(k0 + krow) * 64 + (o & 63)] = t[tx][krow];
    }
}

// ---- down-conv v2 main: X-stationary LDS, parity-decomposed layout ----
__global__ __launch_bounds__(256) void k_down2(const float* __restrict__ X,
                                               const float* __restrict__ WP,
                                               float* __restrict__ part) {
    __shared__ float sX[64 * 256];              // 64 KB
    int tid = threadIdx.x;
    int ot = blockIdx.x, kc = blockIdx.y, b = blockIdx.z;
    int c0 = kc * 64;
    const float* Xg = X + ((size_t)b * 1024 + c0) * 256;
    for (int i = tid; i < 16384; i += 256) {
        int c = i >> 8, px = i & 255;
        int sy = px >> 4, sx = px & 15;
        int par = (sy & 1) * 2 + (sx & 1);
        sX[(c * 4 + par) * 64 + (sy >> 1) * 8 + (sx >> 1)] = Xg[i];
    }
    __syncthreads();
    int lane = tid & 63;
    int w = __builtin_amdgcn_readfirstlane(tid >> 6);
    int oh = lane >> 3, ow = lane & 7;
    int loff[9]; float lmsk[9];
#pragma unroll
    for (int kh = 0; kh < 3; ++kh)
#pragma unroll
        for (int kw = 0; kw < 3; ++kw) {
            int py = (kh == 1) ? 0 : 1;
            int pxp = (kw == 1) ? 0 : 1;
            int u = oh - ((kh == 0) ? 1 : 0);
            int v = ow - ((kw == 0) ? 1 : 0);
            float m = (u >= 0 && v >= 0) ? 1.f : 0.f;
            if (u < 0) u = 0;
            if (v < 0) v = 0;
            loff[kh * 3 + kw] = (py * 2 + pxp) * 64 + u * 8 + v;
            lmsk[kh * 3 + kw] = m;
        }
    float acc[16];
#pragma unroll
    for (int j = 0; j < 16; ++j) acc[j] = 0.f;
    const float* wb = WP + (size_t)ot * 589824 + (size_t)c0 * 576 + w * 16;
    for (int c = 0; c < 64; ++c) {
        const float* xb = sX + c * 256;
        const float* wc = wb + (size_t)c * 576;
#pragma unroll
        for (int tap = 0; tap < 9; ++tap) {
            float xv = xb[loff[tap]] * lmsk[tap];
            const float* wr = wc + tap * 64;
#pragma unroll
            for (int j = 0; j < 16; ++j) acc[j] = fmaf(xv, wr[j], acc[j]);
        }
    }
    float* pp = part + ((size_t)((kc * 2 + b) * 1024 + ot * 64 + w * 16)) * 64 + lane;
#pragma unroll
    for (int j = 0; j < 16; ++j) pp[(size_t)j * 64] = acc[j];
}

// ---- down-conv v2: K-split reduction + bias ----
__global__ __launch_bounds__(256) void k_downred(const float* __restrict__ part,
                                                 const float* __restrict__ bias,
                                                 float* __restrict__ out) {
    int idx = blockIdx.x * 256 + threadIdx.x;   // < 131072 == b*65536 + o*64 + px
    int o = (idx >> 6) & 1023;
    int b = idx >> 16;
    int px = idx & 63;
    float s = bias[o];
#pragma unroll
    for (int kcs = 0; kcs < 16; ++kcs)
        s += part[((size_t)(kcs * 2 + b) * 1024 + o) * 64 + px];
    out[idx] = s;
}

// fused concat -> bf16 CHANNELS-LAST (b, pos4096, ch2816)  [R5-proven 1-elem version]
__global__ void k_fusedcat_bf(const float* __restrict__ f0, const float* __restrict__ f1,
                              const float* __restrict__ f2, const float* __restrict__ f3,
                              short* __restrict__ out) {
    int idx = blockIdx.x * 256 + threadIdx.x;       // < 23068672
    int ch = idx % 2816;
    int t = idx / 2816;
    int pos = t & 4095;
    int b = t >> 12;
    float v;
    if (ch < 256) {
        v = f0[((size_t)(b * 256 + ch)) * 4096 + pos];
    } else {
        const float* src; int sh;
        if (ch < 768)       { src = f1 + ((size_t)(b * 512 + (ch - 256))) * 1024; sh = 32; }
        else if (ch < 1792) { src = f2 + ((size_t)(b * 1024 + (ch - 768))) * 256; sh = 16; }
        else                { src = f3 + ((size_t)(b * 1024 + (ch - 1792))) * 64; sh = 8;  }
        int y = pos >> 6, x = pos & 63;
        float r = (float)(sh - 1) / 63.0f;
        float cy = y * r, cx = x * r;
        int i0 = (int)cy; if (i0 > sh - 2) i0 = sh - 2;
        int j0 = (int)cx; if (j0 > sh - 2) j0 = sh - 2;
        float ty = cy - (float)i0, tx = cx - (float)j0;
        const float* s0 = src + i0 * sh + j0;
        float v00 = s0[0], v01 = s0[1], v10 = s0[sh], v11 = s0[sh + 1];
        float c0 = v00 + ty * (v10 - v00);
        float c1 = v01 + ty * (v11 - v01);
        v = c0 + tx * (c1 - c0);
    }
    out[idx] = f2bf(v);
}

// fuse weight prep: bf16 B-fragment order for 16x16x32 MFMA.
__global__ void k_wfuseprep(const float* __restrict__ w, short* __restrict__ wb) {
    int idx = blockIdx.x * 256 + threadIdx.x;       // < 720896
    int j = idx & 7;
    int lane = (idx >> 3) & 63;
    int ntile = (idx >> 9) & 15;
    int chunk = idx >> 13;                          // < 88
    int oc = ntile * 16 + (lane & 15);
    int c = chunk * 32 + (lane >> 4) * 8 + j;
    wb[idx] = f2bf(w[(size_t)oc * 2816 + c]);
}

// fuse GEMM on MFMA bf16: M=8192 px, N=256 oc, K=2816.
__global__ __launch_bounds__(256) void k_fuse_mfma(const short* __restrict__ A,
                                                   const bf16x8* __restrict__ WB,
                                                   const float* __restrict__ bias,
                                                   short* __restrict__ out) {
    int tid = threadIdx.x;
    int lane = tid & 63, w = tid >> 6;
    int row0 = blockIdx.x * 16;                     // global px row of tile
    int l15 = lane & 15, q = lane >> 4;
    int arow = row0 + l15;
    f32x4 acc[4];
#pragma unroll
    for (int nn = 0; nn < 4; ++nn) acc[nn] = (f32x4){0.f, 0.f, 0.f, 0.f};
    const short* arp = A + (size_t)arow * 2816 + q * 8;
    for (int chunk = 0; chunk < 88; ++chunk) {
        bf16x8 a = *(const bf16x8*)(arp + chunk * 32);
        const bf16x8* wbp = WB + ((size_t)(chunk * 16 + w * 4) * 64) + lane;
#pragma unroll
        for (int nn = 0; nn < 4; ++nn) {
            bf16x8 bf = wbp[nn * 64];
            acc[nn] = __builtin_amdgcn_mfma_f32_16x16x32_bf16(a, bf, acc[nn], 0, 0, 0);
        }
    }
#pragma unroll
    for (int nn = 0; nn < 4; ++nn) {
        int oc = (w * 4 + nn) * 16 + l15;
        float bs = bias[oc];
#pragma unroll
        for (int r = 0; r < 4; ++r) {
            int m = q * 4 + r;
            out[(size_t)(row0 + m) * 256 + oc] = f2bf(fmaxf(acc[nn][r] + bs, 0.f));
        }
    }
}

// bilinear 64->224 on bf16 channels-last, 8 ch per thread
__global__ void k_resize224bf2(const short* __restrict__ in, short* __restrict__ out) {
    int idx = blockIdx.x * 256 + threadIdx.x;       // < 3211264
    int c8 = (idx & 31) * 8;
    int p = idx >> 5;                               // < 100352
    int b = p / NP;
    int pos = p - b * NP;
    int y = pos / HW, x = pos - y * HW;
    const float r = (float)(63.0 / 223.0);
    float cy = y * r, cx = x * r;
    int i0 = (int)cy; if (i0 > 62) i0 = 62;
    int j0 = (int)cx; if (j0 > 62) j0 = 62;
    float ty = cy - (float)i0, tx = cx - (float)j0;
    const short* base = in + ((size_t)b * 4096) * 256 + c8;
    const bf16x8 v00 = *(const bf16x8*)(base + (size_t)(i0 * 64 + j0) * 256);
    const bf16x8 v01 = *(const bf16x8*)(base + (size_t)(i0 * 64 + j0 + 1) * 256);
    const bf16x8 v10 = *(const bf16x8*)(base + (size_t)((i0 + 1) * 64 + j0) * 256);
    const bf16x8 v11 = *(const bf16x8*)(base + (size_t)((i0 + 1) * 64 + j0 + 1) * 256);
    bf16x8 o;
#pragma unroll
    for (int k = 0; k < 8; ++k) {
        float a00 = bf2f(v00[k]), a01 = bf2f(v01[k]);
        float a10 = bf2f(v10[k]), a11 = bf2f(v11[k]);
        float c0 = a00 + ty * (a10 - a00);
        float c1 = a01 + ty * (a11 - a01);
        o[k] = f2bf(c0 + tx * (c1 - c0));
    }
    *(bf16x8*)(out + ((size_t)b * NP + pos) * 256 + c8) = o;
}

// conv1 weight prep: BN-fold + bf16 + MFMA B-fragment order.
__global__ void k_w1prep(const float* __restrict__ w, const float* __restrict__ bias,
                         const float* __restrict__ g, const float* __restrict__ bb,
                         const float* __restrict__ m, const float* __restrict__ v,
                         short* __restrict__ wb, float* __restrict__ shift) {
    int idx = blockIdx.x * 256 + threadIdx.x;      // < 294912
    int j = idx & 7;
    int lane = (idx >> 3) & 63;
    int nt = (idx >> 9) & 7;
    int tc = idx >> 12;
    int tap = tc % 9, chunk = tc / 9;
    int oc = nt * 16 + (lane & 15);
    int c = chunk * 32 + (lane >> 4) * 8 + j;
    float s = g[oc] * rsqrtf(v[oc] + 1e-5f);
    wb[idx] = f2bf(w[((size_t)oc * 256 + c) * 9 + tap] * s);
    if (idx < 128) {
        float si = g[idx] * rsqrtf(v[idx] + 1e-5f);
        shift[idx] = (bias[idx] - m[idx]) * si + bb[idx];
    }
}

// conv1 as implicit GEMM on MFMA bf16 — 8x8 px tiles (2x grid vs 16x8) to
// fix grid-limited occupancy (19.8% -> ~40%): 1568 blocks = 6.1/CU.
__global__ __launch_bounds__(256) void k_conv1mfma(const short* __restrict__ X,
                                                   const bf16x8* __restrict__ WB,
                                                   const float* __restrict__ shift,
                                                   float* __restrict__ out) {
    int tid = threadIdx.x;
    int lane = tid & 63, w = tid >> 6;
    int t = blockIdx.x;                 // < 784 = 28x28 tiles of 8x8
    int b = blockIdx.y;
    int ty0 = (t / 28) * 8, tx0 = (t % 28) * 8;
    int l15 = lane & 15, q = lane >> 4;
    int loc = w * 16 + l15;             // wave w owns px loc in [w*16, w*16+16)
    int py0 = ty0 + (loc >> 3), px0 = tx0 + (loc & 7);
    int csub = q * 8;
    f32x4 acc0[8];
#pragma unroll
    for (int nt = 0; nt < 8; ++nt) acc0[nt] = (f32x4){0.f, 0.f, 0.f, 0.f};
    const short* Xb = X + (size_t)b * NP * 256;
    const bf16x8 zv = {0, 0, 0, 0, 0, 0, 0, 0};
    for (int chunk = 0; chunk < 8; ++chunk) {
        int c0 = chunk * 32 + csub;
#pragma unroll
        for (int tap = 0; tap < 9; ++tap) {
            int dy = tap / 3 - 1, dx = tap % 3 - 1;
            int sy0 = py0 + dy, sx0 = px0 + dx;
            bf16x8 a0 = zv;
            if ((unsigned)sy0 < HW && (unsigned)sx0 < HW)
                a0 = *(const bf16x8*)(Xb + ((size_t)sy0 * HW + sx0) * 256 + c0);
            const bf16x8* wbp = WB + (size_t)((chunk * 9 + tap) * 8) * 64 + lane;
#pragma unroll
            for (int nt = 0; nt < 8; ++nt) {
                bf16x8 bf = wbp[nt * 64];
                acc0[nt] = __builtin_amdgcn_mfma_f32_16x16x32_bf16(a0, bf, acc0[nt], 0, 0, 0);
            }
        }
    }
#pragma unroll
    for (int nt = 0; nt < 8; ++nt) {
        int oc = nt * 16 + l15;
        float sh = shift[oc];
        float* ob = out + ((size_t)(b * 128 + oc)) * NP;
#pragma unroll
        for (int r = 0; r < 4; ++r) {
            int lm = w * 16 + q * 4 + r;
            int py = ty0 + (lm >> 3), px = tx0 + (lm & 7);
            ob[py * HW + px] = fmaxf(acc0[nt][r] + sh, 0.f);
        }
    }
}

// ---- conv3 v3: weight repack (O,C,3,3) -> WP[c][tap][o] ----
__global__ void k_wc3prep(const float* __restrict__ W, float* __restrict__ WP,
                          int C, int O) {
    int idx = blockIdx.x * 256 + threadIdx.x;
    if (idx >= C * 9 * O) return;
    int o = idx % O;
    int t = idx / O;
    int tap = t % 9, c = t / 9;
    WP[idx] = W[((size_t)o * C + c) * 9 + tap];
}

// ---- conv3 v3 main: K-split, all-O-per-block, 32x8 px tile ----
template <int O, int CB>
__global__ __launch_bounds__(256) void k_conv3v3(const float* __restrict__ in,
                                                 const float* __restrict__ WP,
                                                 float* __restrict__ part, int C) {
    __shared__ float sX[8 * 360];               // 8 ch x 10 rows x 36-stride
    int tid = threadIdx.x;
    int tb = blockIdx.x, s = blockIdx.y, b = blockIdx.z;
    int ty0 = (tb / 7) * 8, tx0 = (tb % 7) * 32;
    int px = tid & 31, py = tid >> 5;
    float acc[O];
#pragma unroll
    for (int o = 0; o < O; ++o) acc[o] = 0.f;
    int c0 = s * CB;
    const float* ic = in + ((size_t)b * C + c0) * NP;
    const float* wbase = WP + (size_t)c0 * 9 * O;
    for (int cc = 0; cc < CB; cc += 8) {
        __syncthreads();
        for (int i = tid; i < 8 * 340; i += 256) {
            int c = i / 340;
            int r = i - c * 340;
            int y = r / 34, x = r - y * 34;
            int sy = ty0 + y - 1, sx = tx0 + x - 1;
            float v = 0.f;
            if ((unsigned)sy < HW && (unsigned)sx < HW)
                v = ic[(size_t)(cc + c) * NP + sy * HW + sx];
            sX[c * 360 + y * 36 + x] = v;
        }
        __syncthreads();
        const float* xb = sX + py * 36 + px;
#pragma unroll 1
        for (int c = 0; c < 8; ++c) {
            const float* xc = xb + c * 360;
            const float* wc = wbase + (size_t)(cc + c) * 9 * O;
#pragma unroll
            for (int kh = 0; kh < 3; ++kh)
#pragma unroll
                for (int kw = 0; kw < 3; ++kw) {
                    float xv = xc[kh * 36 + kw];
                    const float* wt = wc + (kh * 3 + kw) * O;
#pragma unroll
                    for (int o = 0; o < O; ++o) acc[o] = fmaf(xv, wt[o], acc[o]);
                }
        }
    }
    int gy = ty0 + py, gx = tx0 + px;
    float* ob = part + ((size_t)(s * BATCH + b) * O) * NP + (size_t)gy * HW + gx;
#pragma unroll
    for (int o = 0; o < O; ++o) ob[(size_t)o * NP] = acc[o];
}

// ---- fused conv2 reduce + bias + sim (prototypes dot) ----
__global__ __launch_bounds__(256) void k_red32sim(const float* __restrict__ part,
                                                  const float* __restrict__ bias,
                                                  const float* __restrict__ proto,
                                                  float* __restrict__ o_pe,
                                                  float* __restrict__ simout) {
    int idx = blockIdx.x * 256 + threadIdx.x;   // < B*NP
    int b = idx / NP, pos = idx - b * NP;
    float v[32];
#pragma unroll
    for (int o = 0; o < 32; ++o) {
        float s = bias[o];
#pragma unroll
        for (int s2 = 0; s2 < 4; ++s2)
            s += part[((size_t)((s2 * BATCH + b) * 32 + o)) * NP + pos];
        v[o] = s;
        o_pe[((size_t)(b * 32 + o)) * NP + pos] = s;
    }
    const float scale = 1.0f / sqrtf(32.0f);
    float* so = simout + (size_t)b * NPROTO * NP + pos;
    for (int q = 0; q < NPROTO; ++q) {
        float acc = 0.f;
#pragma unroll
        for (int e = 0; e < 32; ++e) acc = fmaf(v[e], proto[q * EMBD + e], acc);
        so[(size_t)q * NP] = acc * scale;
    }
}

__global__ void k_init(float* acc) { if (threadIdx.x < 8) acc[threadIdx.x] = 0.f; }

__device__ __forceinline__ float block_reduce_sum(float v) {
    __shared__ float sh[4];
#pragma unroll
    for (int off = 32; off > 0; off >>= 1) v += __shfl_down(v, off);
    int lane = threadIdx.x & 63, wv = threadIdx.x >> 6;
    if (lane == 0) sh[wv] = v;
    __syncthreads();
    return (threadIdx.x == 0) ? (sh[0] + sh[1] + sh[2] + sh[3]) : 0.f;
}

__global__ __launch_bounds__(256) void k_edge(const float* __restrict__ pe,
                                              float* __restrict__ edge,
                                              float* __restrict__ acc) {
    int idx = blockIdx.x * 256 + threadIdx.x;
    int b = idx / NP, pos = idx - b * NP;
    int h = pos / HW, w = pos - h * HW;
    int wn = (w < HW - 1) ? w : HW - 2;
    int hn = (h < HW - 1) ? h : HW - 2;
    const float* pb = pe + (size_t)b * EMBD * NP;
    float sx = 0.f, sy = 0.f;
#pragma unroll 4
    for (int e = 0; e < EMBD; ++e) {
        const float* p = pb + (size_t)e * NP;
        sx += fabsf(p[h * HW + wn] - p[h * HW + wn + 1]);
        sy += fabsf(p[hn * HW + w] - p[hn * HW + HW + w]);
    }
    float ev = (sx + sy) * (0.5f / 32.0f);
    edge[idx] = ev;
    float tot = block_reduce_sum(ev);
    if (threadIdx.x == 0) atomicAdd(acc, tot);
}

// ---- fused 2-pass edge-aware smoothing (LDS-tiled, 16x16 out-tile) ----
__global__ __launch_bounds__(256) void k_smooth2x(const float* __restrict__ sin_,
                                                  const float* __restrict__ edge,
                                                  const float* __restrict__ acc,
                                                  float* __restrict__ sout) {
    __shared__ float sIn[20 * 20];      // origin (oy0-2, ox0-2)
    __shared__ float sE[18 * 18];       // edge at origin (oy0-1, ox0-1)
    __shared__ float s1[18 * 18];       // pass-1 result, origin (oy0-1, ox0-1)
    int tid = threadIdx.x;
    int tile = blockIdx.x, p = blockIdx.y, b = blockIdx.z;
    int oy0 = (tile / 14) * 16, ox0 = (tile % 14) * 16;
    float mean = acc[0] * (1.0f / 100352.0f);
    const float* sc = sin_ + ((size_t)(b * NPROTO + p)) * NP;
    const float* eb = edge + (size_t)b * NP;
    for (int i = tid; i < 400; i += 256) {
        int y = i / 20, x = i - y * 20;
        int gy = oy0 - 2 + y, gx = ox0 - 2 + x;
        float v = 0.f;
        if ((unsigned)gy < HW && (unsigned)gx < HW) v = sc[gy * HW + gx];
        sIn[i] = v;
    }
    for (int i = tid; i < 324; i += 256) {
        int y = i / 18, x = i - y * 18;
        int gy = oy0 - 1 + y, gx = ox0 - 1 + x;
        float e = 0.f;
        if ((unsigned)gy < HW && (unsigned)gx < HW) e = eb[gy * HW + gx];
        sE[i] = e;
    }
    __syncthreads();
    for (int i = tid; i < 324; i += 256) {
        int y = i / 18, x = i - y * 18;
        int gy = oy0 - 1 + y, gx = ox0 - 1 + x;
        float r = 0.f;
        if ((unsigned)gy < HW && (unsigned)gx < HW) {
            const float* c0 = sIn + (y + 1) * 20 + (x + 1);
            float s = c0[-21] + c0[-20] + c0[-19]
                    + c0[-1]  + c0[0]   + c0[1]
                    + c0[19]  + c0[20]  + c0[21];
            float m = (sE[i] > mean) ? 1.f : 0.f;
            r = m * c0[0] + (1.f - m) * (s * (1.0f / 9.0f));
        }
        s1[i] = r;
    }
    __syncthreads();
    {
        int px = tid & 15, py = tid >> 4;
        int gy = oy0 + py, gx = ox0 + px;
        const float* c1 = s1 + (py + 1) * 18 + (px + 1);
        float s = c1[-19] + c1[-18] + c1[-17]
                + c1[-1]  + c1[0]   + c1[1]
                + c1[17]  + c1[18]  + c1[19];
        float m = (sE[(py + 1) * 18 + (px + 1)] > mean) ? 1.f : 0.f;
        sout[((size_t)(b * NPROTO + p)) * NP + (size_t)gy * HW + gx] =
            m * c1[0] + (1.f - m) * (s * (1.0f / 9.0f));
    }
}

__global__ __launch_bounds__(256) void k_entropy(const float* __restrict__ sim,
                                                 float* __restrict__ acc) {
    int idx = blockIdx.x * 256 + threadIdx.x;
    int b = idx / NP, pos = idx - b * NP;
    const float* s = sim + (size_t)b * NPROTO * NP + pos;
    float v[NPROTO];
    float mx = -3.0e38f;
#pragma unroll
    for (int q = 0; q < NPROTO; ++q) { v[q] = s[(size_t)q * NP]; mx = fmaxf(mx, v[q]); }
    float sum = 0.f;
#pragma unroll
    for (int q = 0; q < NPROTO; ++q) { float e = expf(v[q] - mx); v[q] = e; sum += e; }
    float inv = 1.f / sum;
    float ent = 0.f;
#pragma unroll
    for (int q = 0; q < NPROTO; ++q) {
        float a = v[q] * inv;
        ent -= a * logf(a + 1e-8f);
    }
    float tot = block_reduce_sum(ent);
    if (threadIdx.x == 0) atomicAdd(acc + 1, tot);
}

__global__ void k_bb(const float* __restrict__ pb, const float* __restrict__ bs,
                     float* __restrict__ bbuf, float* __restrict__ obb) {
    int t = threadIdx.x;
    if (t < NPROTO) {
        float v = 1.f + tanhf(pb[t]) * bs[0];
        bbuf[t] = v;
        obb[t] = v;
        obb[NPROTO + t] = v;
    }
}

// ---- fused smooth-conv reduce + bias + softmax + act + bgain ----
__global__ __launch_bounds__(256) void k_actsm2(const float* __restrict__ part,
                                                const float* __restrict__ bias,
                                                const float* __restrict__ bb,
                                                float* __restrict__ act,
                                                float* __restrict__ bgain) {
    int idx = blockIdx.x * 256 + threadIdx.x;
    int b = idx / NP, pos = idx - b * NP;
    float v[NPROTO];
    float mx = -3.0e38f;
#pragma unroll
    for (int q = 0; q < NPROTO; ++q) {
        float s = bias[q];
        s += part[((size_t)((0 * BATCH + b) * NPROTO + q)) * NP + pos];
        s += part[((size_t)((1 * BATCH + b) * NPROTO + q)) * NP + pos];
        v[q] = s;
        mx = fmaxf(mx, s);
    }
    float sum = 0.f;
#pragma unroll
    for (int q = 0; q < NPROTO; ++q) { float e = expf(v[q] - mx); v[q] = e; sum += e; }
    float inv = 1.f / sum;
    float* a = act + (size_t)b * NPROTO * NP + pos;
    float bg = 0.f;
#pragma unroll
    for (int q = 0; q < NPROTO; ++q) {
        float p = v[q] * inv;
        a[(size_t)q * NP] = p;
        bg = fmaf(p, bb[q], bg);
    }
    bgain[idx] = bg;
}

__global__ void k_headprep(const float* __restrict__ w1, const float* __restrict__ b1,
                           const float* __restrict__ g1, const float* __restrict__ be1,
                           const float* __restrict__ m1, const float* __restrict__ v1,
                           const float* __restrict__ w2, const float* __restrict__ b2,
                           const float* __restrict__ g2, const float* __restrict__ be2,
                           const float* __restrict__ m2, const float* __restrict__ v2,
                           float* __restrict__ wf) {
    int oc = blockIdx.x * 256 + threadIdx.x;
    if (oc >= 512) return;
    float s1 = g1[oc] * rsqrtf(v1[oc] + 1e-5f);
#pragma unroll
    for (int k = 0; k < 9; ++k) wf[oc * 9 + k] = w1[oc * 9 + k] * s1;
    wf[41472 + oc] = (b1[oc] - m1[oc]) * s1 + be1[oc];
    float s2 = g2[oc] * rsqrtf(v2[oc] + 1e-5f);
    int g = oc >> 3, j = oc & 7;
#pragma unroll
    for (int icc = 0; icc < 8; ++icc)
#pragma unroll
        for (int k = 0; k < 9; ++k)
            wf[4608 + (size_t)g * 576 + icc * 72 + j * 9 + k] = w2[((size_t)oc * 8 + icc) * 9 + k] * s2;
    wf[41984 + oc] = (b2[oc] - m2[oc]) * s2 + be2[oc];
}

// fused 3-layer grouped heads, 16x16 out-tile (R4 verified version).
__global__ __launch_bounds__(256) void k_heads(
    const float* __restrict__ act, const float* __restrict__ wf,
    const float* __restrict__ w3, const float* __restrict__ b3,
    float* __restrict__ res) {
    __shared__ float sA[22 * 24];           // origin (oy0-3, ox0-3), stride 24
    __shared__ float sH1[8][20 * 22];       // origin (oy0-2, ox0-2), stride 22
    __shared__ float sH2[8][18 * 18];       // origin (oy0-1, ox0-1), stride 18
    int tid = threadIdx.x;
    int tile = blockIdx.x, g = blockIdx.y, b = blockIdx.z;
    int oy0 = (tile / 14) * 16, ox0 = (tile % 14) * 16;
    const float* ain = act + (size_t)(b * NPROTO + g) * NP;

    for (int i = tid; i < 484; i += 256) {
        int y = i / 22, x = i - y * 22;
        int gy = oy0 - 3 + y, gx = ox0 - 3 + x;
        float v = 0.f;
        if ((unsigned)gy < HW && (unsigned)gx < HW) v = ain[gy * HW + gx];
        sA[y * 24 + x] = v;
    }
    __syncthreads();

    // stage1: 20x20, 1 px/thread
    const float* b1f = wf + 41472 + g * 8;
    for (int i = tid; i < 400; i += 256) {
        int y = i / 20, x = i - y * 20;
        int gy = oy0 - 2 + y, gx = ox0 - 2 + x;
        float keep = ((unsigned)gy < HW && (unsigned)gx < HW) ? 1.f : 0.f;
        const float* s0 = sA + y * 24 + x;
        float r0 = s0[0],  r1 = s0[1],  r2 = s0[2];
        float r3 = s0[24], r4 = s0[25], r5 = s0[26];
        float r6 = s0[48], r7 = s0[49], r8 = s0[50];
#pragma unroll
        for (int j = 0; j < 8; ++j) {
            const float* w = wf + (g * 8 + j) * 9;
            float v = fmaf(r0, w[0], fmaf(r1, w[1], fmaf(r2, w[2],
                      fmaf(r3, w[3], fmaf(r4, w[4], fmaf(r5, w[5],
                      fmaf(r6, w[6], fmaf(r7, w[7], fmaf(r8, w[8], b1f[j])))))))));
            sH1[j][y * 22 + x] = fmaxf(v, 0.f) * keep;
        }
    }
    __syncthreads();

    // stage2: 18x18 as 18x9 pixel pairs, f32x2 packed
    const float* w2f = wf + 4608 + (size_t)g * 576;
    const float* b2f = wf + 41984 + g * 8;
    if (tid < 162) {
        int y2 = tid / 9, xp = (tid - y2 * 9) * 2;
        f32x2 a2[8];
#pragma unroll
        for (int j = 0; j < 8; ++j) { float bv = b2f[j]; a2[j] = (f32x2){bv, bv}; }
#pragma unroll
        for (int icc = 0; icc < 8; ++icc) {
            const float* s0 = &sH1[icc][y2 * 22 + xp];
            f32x2 t[9];
#pragma unroll
            for (int r = 0; r < 3; ++r) {
                float f0 = s0[r * 22], f1 = s0[r * 22 + 1];
                float f2 = s0[r * 22 + 2], f3 = s0[r * 22 + 3];
                t[r * 3 + 0] = (f32x2){f0, f1};
                t[r * 3 + 1] = (f32x2){f1, f2};
                t[r * 3 + 2] = (f32x2){f2, f3};
            }
            const float* wr = w2f + icc * 72;
#pragma unroll
            for (int j = 0; j < 8; ++j) {
                const float* wj = wr + j * 9;
#pragma unroll
                for (int k = 0; k < 9; ++k) {
                    float wv = wj[k];
                    a2[j] = __builtin_elementwise_fma(t[k], (f32x2){wv, wv}, a2[j]);
                }
            }
        }
        int gy = oy0 - 1 + y2;
        int gx0 = ox0 - 1 + xp;
        float k0 = ((unsigned)gy < HW && (unsigned)gx0 < HW) ? 1.f : 0.f;
        float k1 = ((unsigned)gy < HW && (unsigned)(gx0 + 1) < HW) ? 1.f : 0.f;
        f32x2 kp = (f32x2){k0, k1};
        const f32x2 z2 = (f32x2){0.f, 0.f};
#pragma unroll
        for (int j = 0; j < 8; ++j) {
            f32x2 v = __builtin_elementwise_max(a2[j], z2) * kp;
            sH2[j][y2 * 18 + xp] = v.x;
            sH2[j][y2 * 18 + xp + 1] = v.y;
        }
    }
    __syncthreads();

    // stage3: 16x16 as 16x8 pairs, f32x2 packed
    if (tid < 128) {
        int y3 = tid >> 3, xp = (tid & 7) * 2;
        float bv = b3[g];
        f32x2 a2 = (f32x2){bv, bv};
#pragma unroll
        for (int icc = 0; icc < 8; ++icc) {
            const float* s0 = &sH2[icc][y3 * 18 + xp];
            const float* w = w3 + (size_t)(g * 8 + icc) * 9;
#pragma unroll
            for (int r = 0; r < 3; ++r) {
                float f0 = s0[r * 18], f1 = s0[r * 18 + 1];
                float f2 = s0[r * 18 + 2], f3 = s0[r * 18 + 3];
                float w0 = w[r * 3], w1 = w[r * 3 + 1], w2v = w[r * 3 + 2];
                a2 = __builtin_elementwise_fma((f32x2){f0, f1}, (f32x2){w0, w0}, a2);
                a2 = __builtin_elementwise_fma((f32x2){f1, f2}, (f32x2){w1, w1}, a2);
                a2 = __builtin_elementwise_fma((f32x2){f2, f3}, (f32x2){w2v, w2v}, a2);
            }
        }
        float* rp = res + (size_t)(b * NPROTO + g) * NP + (size_t)(oy0 + y3) * HW + (ox0 + xp);
        rp[0] = a2.x;
        rp[1] = a2.y;
    }
}

__global__ __launch_bounds__(256) void k_final(const float* __restrict__ act,
                                               const float* __restrict__ res,
                                               const float* __restrict__ bgain,
                                               const float* __restrict__ rscale,
                                               float* __restrict__ owt,
                                               float* __restrict__ oibm) {
    int idx = blockIdx.x * 256 + threadIdx.x;
    int b = idx / NP, pos = idx - b * NP;
    const float* a = act + (size_t)b * NPROTO * NP + pos;
    const float* r = res + (size_t)b * NPROTO * NP + pos;
    float wt = 0.f;
#pragma unroll
    for (int q = 0; q < NPROTO; ++q) wt = fmaf(a[(size_t)q * NP], r[(size_t)q * NP], wt);
    owt[idx] = wt;
    float gn = bgain[idx] * (1.f + tanhf(wt) * rscale[0]);
    gn = fminf(fmaxf(gn, 0.5f), 2.0f);
    oibm[idx] = gn;
}

__global__ void k_entfinal(const float* __restrict__ acc, float* __restrict__ o) {
    if (threadIdx.x == 0) o[0] = acc[1] * (1.0f / 100352.0f);
}

// ======================================================================
extern "C" void kernel_launch(void* const* d_in, const int* in_sizes, int n_in,
                              void* d_out, int out_size, void* d_ws, size_t ws_size,
                              hipStream_t stream) {
    const float* tokens[4] = {(const float*)d_in[0], (const float*)d_in[1],
                              (const float*)d_in[2], (const float*)d_in[3]};
    const float* proj_w[4] = {(const float*)d_in[4], (const float*)d_in[6],
                              (const float*)d_in[8], (const float*)d_in[10]};
    const float* proj_b[4] = {(const float*)d_in[5], (const float*)d_in[7],
                              (const float*)d_in[9], (const float*)d_in[11]};
    const float* up_w0 = (const float*)d_in[12]; const float* up_b0 = (const float*)d_in[13];
    const float* up_w1 = (const float*)d_in[14]; const float* up_b1 = (const float*)d_in[15];
    const float* down_w3 = (const float*)d_in[16]; const float* down_b3 = (const float*)d_in[17];
    const float* fuse_w = (const float*)d_in[18]; const float* fuse_b = (const float*)d_in[19];
    const float* pe_w1 = (const float*)d_in[20]; const float* pe_b1 = (const float*)d_in[21];
    const float* pe_bn_g = (const float*)d_in[22]; const float* pe_bn_b = (const float*)d_in[23];
    const float* pe_bn_m = (const float*)d_in[24]; const float* pe_bn_v = (const float*)d_in[25];
    const float* pe_w2 = (const float*)d_in[26]; const float* pe_b2 = (const float*)d_in[27];
    const float* prototypes = (const float*)d_in[28];
    const float* proto_biases = (const float*)d_in[29];
    const float* bias_scale = (const float*)d_in[30];
    const float* smooth_w = (const float*)d_in[31]; const float* smooth_b = (const float*)d_in[32];
    const float* hw1 = (const float*)d_in[33]; const float* hb1 = (const float*)d_in[34];
    const float* hg1 = (const float*)d_in[35]; const float* hbe1 = (const float*)d_in[36];
    const float* hm1 = (const float*)d_in[37]; const float* hv1 = (const float*)d_in[38];
    const float* hw2 = (const float*)d_in[39]; const float* hb2 = (const float*)d_in[40];
    const float* hg2 = (const float*)d_in[41]; const float* hbe2 = (const float*)d_in[42];
    const float* hm2 = (const float*)d_in[43]; const float* hv2 = (const float*)d_in[44];
    const float* hw3 = (const float*)d_in[45]; const float* hb3 = (const float*)d_in[46];
    const float* rscale = (const float*)d_in[47];
    (void)in_sizes; (void)n_in; (void)out_size; (void)ws_size;

    float* ws = (float*)d_ws;
    float* FEATS[4] = {ws + OFF_FEATS0, ws + OFF_FEATS1, ws + OFF_FEATS2, ws + OFF_FEATS3};
    float* TOKT = ws + OFF_TOKT;
    float* F0 = ws + OFF_F0; float* F1 = ws + OFF_F1; float* F3 = ws + OFF_F3;
    short* FUSEDBF = (short*)(ws + OFF_FUSEDBF);
    short* P64C = (short*)(ws + OFF_P64C);
    short* P224C = (short*)(ws + OFF_P224C);
    short* WB = (short*)(ws + OFF_WB);
    short* WFUSE = (short*)(ws + OFF_WFUSE);
    float* SHIFT = ws + OFF_SHIFT;
    float* T1 = ws + OFF_T1;
    float* SIMA = ws + OFF_SIMA;
    float* SIMRAW = ws + OFF_SIMRAW;
    float* EDGE = ws + OFF_EDGE; float* RES = ws + OFF_RES;
    float* BGAIN = ws + OFF_BGAIN; float* BBUF = ws + OFF_BB; float* ACC = ws + OFF_ACC;
    float* WF = ws + OFF_WF;
    float* WDP = ws + OFF_WD;
    float* PART = ws + OFF_PART;
    float* WCV0 = ws + OFF_WCV0;
    float* WCV1 = ws + OFF_WCV1;
    float* WC2 = ws + OFF_WC2;
    float* WSM = ws + OFF_WSM;
    float* PC2 = ws + OFF_PC2;      // conv2 partials (dead-P224C window)
    float* PSM = ws + OFF_PSM;      // smooth partials (dead-T1/SIMRAW window)

    float* out = (float*)d_out;
    float* o_ibm = out + O_IBM; float* o_act = out + O_ACT; float* o_bb = out + O_BB;
    float* o_wt = out + O_WT; float* o_pe = out + O_PE; float* o_ent = out + O_ENT;

    const int OCH[4] = {256, 512, 1024, 1024};
    for (int s = 0; s < 4; ++s)
        k_transpose<<<768, 256, 0, stream>>>(tokens[s], TOKT + s * 196608);
    for (int s = 0; s < 4; ++s)
        k_proj<<<dim3(OCH[s], BATCH), 256, 0, stream>>>(TOKT + s * 196608, proj_w[s], proj_b[s],
                                                        FEATS[s], OCH[s]);
    // convT v2: pack W (C x M tiled transpose), then LDS-GEMM
    k_wcvprep<16><<<dim3(8, 128), 256, 0, stream>>>(up_w0, WCV0, 256, 4096);
    k_wcvprep<8><<<dim3(16, 64), 256, 0, stream>>>(up_w1, WCV1, 512, 2048);
    k_convt2<16, 64, 4><<<dim3(256, BATCH), 256, 0, stream>>>(FEATS[0], WCV0, up_b0, F0, 256, 256);
    k_convt2<8, 64, 2><<<dim3(256, BATCH), 256, 0, stream>>>(FEATS[1], WCV1, up_b1, F1, 512, 512);
    // down-conv v2: pack W, K-split GEMM, reduce (+bias)
    k_wdprep<<<dim3(288, 32), 256, 0, stream>>>(down_w3, WDP);
    k_down2<<<dim3(16, 16, BATCH), 256, 0, stream>>>(FEATS[3], WDP, PART);
    k_downred<<<512, 256, 0, stream>>>(PART, down_b3, F3);
    // conv3 v3 weight packs (early, independent)
    k_wc3prep<<<144, 256, 0, stream>>>(pe_w2, WC2, 128, 32);
    k_wc3prep<<<144, 256, 0, stream>>>(smooth_w, WSM, 64, 64);
    k_wfuseprep<<<2816, 256, 0, stream>>>(fuse_w, WFUSE);
    k_fusedcat_bf<<<90112, 256, 0, stream>>>(F0, F1, FEATS[2], F3, FUSEDBF);
    k_fuse_mfma<<<512, 256, 0, stream>>>(FUSEDBF, (const bf16x8*)WFUSE, fuse_b, P64C);
    // FUSEDBF dead: WB/SHIFT (inside its range) safe now
    k_w1prep<<<1152, 256, 0, stream>>>(pe_w1, pe_b1, pe_bn_g, pe_bn_b, pe_bn_m, pe_bn_v,
                                       WB, SHIFT);
    k_resize224bf2<<<12544, 256, 0, stream>>>(P64C, P224C);
    // conv1: 8x8 px tiles, 1568 blocks (occupancy fix)
    k_conv1mfma<<<dim3(784, BATCH), 256, 0, stream>>>(P224C, (const bf16x8*)WB, SHIFT, T1);
    // conv2: K-split 4 (P224C dead -> PC2 window free)
    k_conv3v3<32, 32><<<dim3(196, 4, BATCH), 256, 0, stream>>>(T1, WC2, PC2, 128);
    // fused reduce+sim: raw sim -> SIMRAW (dead-T1 window; T1 consumed above)
    k_red32sim<<<392, 256, 0, stream>>>(PC2, pe_b2, prototypes, o_pe, SIMRAW);
    k_init<<<1, 64, 0, stream>>>(ACC);
    k_edge<<<392, 256, 0, stream>>>(o_pe, EDGE, ACC);
    // fused 2-pass smoothing: SIMRAW -> SIMA (PC2 dead; disjoint buffers, no race)
    k_smooth2x<<<dim3(196, NPROTO, BATCH), 256, 0, stream>>>(SIMRAW, EDGE, ACC, SIMA);
    k_entropy<<<392, 256, 0, stream>>>(SIMA, ACC);
    // smooth conv: K-split 2 (SIMRAW dead -> PSM window free)
    k_conv3v3<64, 32><<<dim3(196, 2, BATCH), 256, 0, stream>>>(SIMA, WSM, PSM, 64);
    k_bb<<<1, 64, 0, stream>>>(proto_biases, bias_scale, BBUF, o_bb);
    // fused reduce+softmax+act+bgain
    k_actsm2<<<392, 256, 0, stream>>>(PSM, smooth_b, BBUF, o_act, BGAIN);
    k_headprep<<<2, 256, 0, stream>>>(hw1, hb1, hg1, hbe1, hm1, hv1,
                                      hw2, hb2, hg2, hbe2, hm2, hv2, WF);
    k_heads<<<dim3(196, 64, BATCH), 256, 0, stream>>>(o_act, WF, hw3, hb3, RES);
    k_final<<<392, 256, 0, stream>>>(o_act, RES, BGAIN, rscale, o_wt, o_ibm);
    k_entfinal<<<1, 1, 0, stream>>>(ACC, o_ent);
}

// Round 11
// 1447.526 us; speedup vs baseline: 1.1061x; 1.0544x over previous
//
#include <hip/hip_runtime.h>
#include <math.h>

// ---------------- problem constants ----------------
#define BATCH 2
#define NTOK 256
#define INCH 384
#define NP 50176          // 224*224
#define HW 224
#define NPROTO 64
#define EMBD 32

// ---------------- workspace layout (floats) ----------------
#define OFF_FEATS0   0u
#define OFF_FEATS1   131072u
#define OFF_FEATS2   393216u
#define OFF_FEATS3   917504u
#define OFF_TOKT     1441792u
#define OFF_F0       2228224u
#define OFF_F1       4325376u
#define OFF_F3       5373952u
#define OFF_FUSEDBF  5505024u      // (2,4096,2816) bf16 = 11.53M fl -> ends 17.04M
#define OFF_WD       5505024u      // down-conv packed weights (9.44M fl) — dead-FUSEDBF window
#define OFF_PART     14942208u     // down-conv K-split partials (2.10M fl) -> ends 17039360
#define OFF_P64C     28573696u     // (2,4096,256) bf16 channels-last
#define OFF_P224C    0u            // (2,224,224,256) bf16 = 12.85M fl
#define OFF_T1       25690112u     // (2,128,224,224) fp32
#define OFF_PC2      0u            // conv2 K-split partials (4x2x32xNP = 12.85M fl, dead-P224C window)
#define OFF_SIMRAW   25690112u     // raw sim (2x64xNP = 6.42M fl, dead-T1 window)
#define OFF_PSM      25690112u     // smooth-conv K-split partials (2x2x64xNP, dead after SIMRAW consumed)
#define OFF_SIMA     0u
#define OFF_EDGE     12845056u
#define OFF_RES      13000000u
#define OFF_WB       13000000u     // conv1 MFMA weight frags (dead-RES window, written after fuse)
#define OFF_SHIFT    13200000u
#define OFF_BGAIN    19422528u
#define OFF_BB       19522880u
#define OFF_ACC      19523008u
#define OFF_WF       19523072u     // folded head weights (42496 fl)
#define OFF_WFUSE    20000000u     // fuse MFMA weight frags: 720896 bf16 = 360448 fl
#define OFF_WCV0     20500000u     // convT F0 packed W: 1048576 fl
#define OFF_WCV1     21600000u     // convT F1 packed W: 1048576 fl -> ends 22.65M
#define OFF_WC2      22700000u     // conv2 packed W [c][tap][o]: 36864 fl
#define OFF_WSM      22750000u     // smooth packed W [c][tap][o]: 36864 fl -> ends 22.79M (< T1 @25.69M)

// ---------------- output layout ----------------
#define O_IBM 0u
#define O_ACT 100352u
#define O_BB  6522880u
#define O_WT  6523008u
#define O_PE  6623360u
#define O_ENT 9834624u

typedef __attribute__((ext_vector_type(8))) short bf16x8;
typedef __attribute__((ext_vector_type(4))) float f32x4;
typedef __attribute__((ext_vector_type(2))) float f32x2;

__device__ __forceinline__ short f2bf(float f) {
    unsigned u = __float_as_uint(f);
    unsigned r = (u + 0x7fffu + ((u >> 16) & 1u)) >> 16;
    return (short)r;
}
__device__ __forceinline__ float bf2f(short s) {
    return __uint_as_float(((unsigned)(unsigned short)s) << 16);
}

// ======================================================================
__global__ void k_transpose(const float* __restrict__ in, float* __restrict__ out) {
    int idx = blockIdx.x * 256 + threadIdx.x;
    int n = idx & 255;
    int c = (idx >> 8) % INCH;
    int b = idx / (INCH * NTOK);
    out[idx] = in[(size_t)b * INCH * NTOK + (size_t)n * INCH + c];
}

__global__ __launch_bounds__(256) void k_proj(const float* __restrict__ A,
                                              const float* __restrict__ W,
                                              const float* __restrict__ bias,
                                              float* __restrict__ out, int O) {
    int p = threadIdx.x;
    int o = blockIdx.x, b = blockIdx.y;
    const float* a = A + (size_t)b * INCH * NTOK + p;
    const float* w = W + (size_t)o * INCH;
    float acc = bias[o];
    for (int c = 0; c < INCH; ++c) acc = fmaf(a[(size_t)c * NTOK], w[c], acc);
    out[((size_t)b * O + o) * NTOK + p] = acc;
}

// ---- convT v2: W repack (tiled transpose) ----
template <int NT>
__global__ __launch_bounds__(256) void k_wcvprep(const float* __restrict__ W,
                                                 float* __restrict__ WP, int C, int M) {
    __shared__ float t[32][33];
    int c0 = blockIdx.x * 32, m0 = blockIdx.y * 32;
    int tx = threadIdx.x & 31, ty = threadIdx.x >> 5;
#pragma unroll
    for (int r = 0; r < 4; ++r) {
        int cl = ty + r * 8;
        t[cl][tx] = W[(size_t)(c0 + cl) * M + m0 + tx];
    }
    __syncthreads();
    for (int i = threadIdx.x; i < 1024; i += 256) {
        int ml = i % NT;
        int tmp = i / NT;
        int cl = tmp & 31;
        int mh = tmp >> 5;
        WP[(size_t)(m0 / NT + mh) * C * NT + (size_t)(c0 + cl) * NT + ml] = t[cl][mh * NT + ml];
    }
}

// ---- convT v2 main: X-stationary LDS GEMM ----
template <int NT, int CCH, int K>
__global__ __launch_bounds__(256) void k_convt2(const float* __restrict__ X,
                                                const float* __restrict__ WP,
                                                const float* __restrict__ bias,
                                                float* __restrict__ out,
                                                int C, int O) {
    __shared__ float sX[CCH * 256];
    int tid = threadIdx.x;
    int nt = blockIdx.x, b = blockIdx.y;
    float acc[NT];
#pragma unroll
    for (int j = 0; j < NT; ++j) acc[j] = 0.f;
    const float* Xb = X + (size_t)b * C * 256;
    for (int cc = 0; cc < C; cc += CCH) {
        __syncthreads();
        const f32x4* Xg4 = (const f32x4*)(Xb + (size_t)cc * 256);
        f32x4* s4 = (f32x4*)sX;
        for (int i = tid; i < CCH * 64; i += 256) s4[i] = Xg4[i];
        __syncthreads();
        const float* wr = WP + ((size_t)nt * C + cc) * NT;
        for (int c = 0; c < CCH; ++c) {
            float xv = sX[c * 256 + tid];
            const float* w = wr + c * NT;
#pragma unroll
            for (int j = 0; j < NT; ++j) acc[j] = fmaf(xv, w[j], acc[j]);
        }
    }
    int h = tid >> 4, w = tid & 15;
    int S = 16 * K;
#pragma unroll
    for (int j = 0; j < NT; ++j) {
        int m = nt * NT + j;
        int o = m / (K * K);
        int ij = m - o * (K * K);
        int ii = ij / K, jj = ij - ii * K;
        out[((size_t)b * O + o) * (size_t)(S * S) + (h * K + ii) * S + (w * K + jj)] =
            acc[j] + bias[o];
    }
}

// ---- down-conv v2: W repack (tiled transpose) ----
__global__ __launch_bounds__(256) void k_wdprep(const float* __restrict__ W,
                                                float* __restrict__ WP) {
    __shared__ float t[32][33];
    int k0 = blockIdx.x * 32, o0 = blockIdx.y * 32;
    int tx = threadIdx.x & 31, ty = threadIdx.x >> 5;
#pragma unroll
    for (int r = 0; r < 4; ++r) {
        int orow = ty + r * 8;
        t[orow][tx] = W[(size_t)(o0 + orow) * 9216 + k0 + tx];
    }
    __syncthreads();
#pragma unroll
    for (int r = 0; r < 4; ++r) {
        int krow = ty + r * 8;
        int o = o0 + tx;
        WP[(size_t)(o >> 6) * 589824 + (size_t)(k0 + krow) * 64 + (o & 63)] = t[tx][krow];
    }
}

// ---- down-conv v2 main: X-stationary LDS, parity-decomposed layout ----
__global__ __launch_bounds__(256) void k_down2(const float* __restrict__ X,
                                               const float* __restrict__ WP,
                                               float* __restrict__ part) {
    __shared__ float sX[64 * 256];              // 64 KB
    int tid = threadIdx.x;
    int ot = blockIdx.x, kc = blockIdx.y, b = blockIdx.z;
    int c0 = kc * 64;
    const float* Xg = X + ((size_t)b * 1024 + c0) * 256;
    for (int i = tid; i < 16384; i += 256) {
        int c = i >> 8, px = i & 255;
        int sy = px >> 4, sx = px & 15;
        int par = (sy & 1) * 2 + (sx & 1);
        sX[(c * 4 + par) * 64 + (sy >> 1) * 8 + (sx >> 1)] = Xg[i];
    }
    __syncthreads();
    int lane = tid & 63;
    int w = __builtin_amdgcn_readfirstlane(tid >> 6);
    int oh = lane >> 3, ow = lane & 7;
    int loff[9]; float lmsk[9];
#pragma unroll
    for (int kh = 0; kh < 3; ++kh)
#pragma unroll
        for (int kw = 0; kw < 3; ++kw) {
            int py = (kh == 1) ? 0 : 1;
            int pxp = (kw == 1) ? 0 : 1;
            int u = oh - ((kh == 0) ? 1 : 0);
            int v = ow - ((kw == 0) ? 1 : 0);
            float m = (u >= 0 && v >= 0) ? 1.f : 0.f;
            if (u < 0) u = 0;
            if (v < 0) v = 0;
            loff[kh * 3 + kw] = (py * 2 + pxp) * 64 + u * 8 + v;
            lmsk[kh * 3 + kw] = m;
        }
    float acc[16];
#pragma unroll
    for (int j = 0; j < 16; ++j) acc[j] = 0.f;
    const float* wb = WP + (size_t)ot * 589824 + (size_t)c0 * 576 + w * 16;
    for (int c = 0; c < 64; ++c) {
        const float* xb = sX + c * 256;
        const float* wc = wb + (size_t)c * 576;
#pragma unroll
        for (int tap = 0; tap < 9; ++tap) {
            float xv = xb[loff[tap]] * lmsk[tap];
            const float* wr = wc + tap * 64;
#pragma unroll
            for (int j = 0; j < 16; ++j) acc[j] = fmaf(xv, wr[j], acc[j]);
        }
    }
    float* pp = part + ((size_t)((kc * 2 + b) * 1024 + ot * 64 + w * 16)) * 64 + lane;
#pragma unroll
    for (int j = 0; j < 16; ++j) pp[(size_t)j * 64] = acc[j];
}

// ---- down-conv v2: K-split reduction + bias ----
__global__ __launch_bounds__(256) void k_downred(const float* __restrict__ part,
                                                 const float* __restrict__ bias,
                                                 float* __restrict__ out) {
    int idx = blockIdx.x * 256 + threadIdx.x;   // < 131072 == b*65536 + o*64 + px
    int o = (idx >> 6) & 1023;
    int b = idx >> 16;
    int px = idx & 63;
    float s = bias[o];
#pragma unroll
    for (int kcs = 0; kcs < 16; ++kcs)
        s += part[((size_t)(kcs * 2 + b) * 1024 + o) * 64 + px];
    out[idx] = s;
}

// fused concat -> bf16 CHANNELS-LAST (b, pos4096, ch2816)  [R5-proven 1-elem version]
__global__ void k_fusedcat_bf(const float* __restrict__ f0, const float* __restrict__ f1,
                              const float* __restrict__ f2, const float* __restrict__ f3,
                              short* __restrict__ out) {
    int idx = blockIdx.x * 256 + threadIdx.x;       // < 23068672
    int ch = idx % 2816;
    int t = idx / 2816;
    int pos = t & 4095;
    int b = t >> 12;
    float v;
    if (ch < 256) {
        v = f0[((size_t)(b * 256 + ch)) * 4096 + pos];
    } else {
        const float* src; int sh;
        if (ch < 768)       { src = f1 + ((size_t)(b * 512 + (ch - 256))) * 1024; sh = 32; }
        else if (ch < 1792) { src = f2 + ((size_t)(b * 1024 + (ch - 768))) * 256; sh = 16; }
        else                { src = f3 + ((size_t)(b * 1024 + (ch - 1792))) * 64; sh = 8;  }
        int y = pos >> 6, x = pos & 63;
        float r = (float)(sh - 1) / 63.0f;
        float cy = y * r, cx = x * r;
        int i0 = (int)cy; if (i0 > sh - 2) i0 = sh - 2;
        int j0 = (int)cx; if (j0 > sh - 2) j0 = sh - 2;
        float ty = cy - (float)i0, tx = cx - (float)j0;
        const float* s0 = src + i0 * sh + j0;
        float v00 = s0[0], v01 = s0[1], v10 = s0[sh], v11 = s0[sh + 1];
        float c0 = v00 + ty * (v10 - v00);
        float c1 = v01 + ty * (v11 - v01);
        v = c0 + tx * (c1 - c0);
    }
    out[idx] = f2bf(v);
}

// fuse weight prep: bf16 B-fragment order for 16x16x32 MFMA.
__global__ void k_wfuseprep(const float* __restrict__ w, short* __restrict__ wb) {
    int idx = blockIdx.x * 256 + threadIdx.x;       // < 720896
    int j = idx & 7;
    int lane = (idx >> 3) & 63;
    int ntile = (idx >> 9) & 15;
    int chunk = idx >> 13;                          // < 88
    int oc = ntile * 16 + (lane & 15);
    int c = chunk * 32 + (lane >> 4) * 8 + j;
    wb[idx] = f2bf(w[(size_t)oc * 2816 + c]);
}

// fuse GEMM on MFMA bf16: M=8192 px, N=256 oc, K=2816.
__global__ __launch_bounds__(256) void k_fuse_mfma(const short* __restrict__ A,
                                                   const bf16x8* __restrict__ WB,
                                                   const float* __restrict__ bias,
                                                   short* __restrict__ out) {
    int tid = threadIdx.x;
    int lane = tid & 63, w = tid >> 6;
    int row0 = blockIdx.x * 16;                     // global px row of tile
    int l15 = lane & 15, q = lane >> 4;
    int arow = row0 + l15;
    f32x4 acc[4];
#pragma unroll
    for (int nn = 0; nn < 4; ++nn) acc[nn] = (f32x4){0.f, 0.f, 0.f, 0.f};
    const short* arp = A + (size_t)arow * 2816 + q * 8;
    for (int chunk = 0; chunk < 88; ++chunk) {
        bf16x8 a = *(const bf16x8*)(arp + chunk * 32);
        const bf16x8* wbp = WB + ((size_t)(chunk * 16 + w * 4) * 64) + lane;
#pragma unroll
        for (int nn = 0; nn < 4; ++nn) {
            bf16x8 bf = wbp[nn * 64];
            acc[nn] = __builtin_amdgcn_mfma_f32_16x16x32_bf16(a, bf, acc[nn], 0, 0, 0);
        }
    }
#pragma unroll
    for (int nn = 0; nn < 4; ++nn) {
        int oc = (w * 4 + nn) * 16 + l15;
        float bs = bias[oc];
#pragma unroll
        for (int r = 0; r < 4; ++r) {
            int m = q * 4 + r;
            out[(size_t)(row0 + m) * 256 + oc] = f2bf(fmaxf(acc[nn][r] + bs, 0.f));
        }
    }
}

// bilinear 64->224 on bf16 channels-last, 8 ch per thread
__global__ void k_resize224bf2(const short* __restrict__ in, short* __restrict__ out) {
    int idx = blockIdx.x * 256 + threadIdx.x;       // < 3211264
    int c8 = (idx & 31) * 8;
    int p = idx >> 5;                               // < 100352
    int b = p / NP;
    int pos = p - b * NP;
    int y = pos / HW, x = pos - y * HW;
    const float r = (float)(63.0 / 223.0);
    float cy = y * r, cx = x * r;
    int i0 = (int)cy; if (i0 > 62) i0 = 62;
    int j0 = (int)cx; if (j0 > 62) j0 = 62;
    float ty = cy - (float)i0, tx = cx - (float)j0;
    const short* base = in + ((size_t)b * 4096) * 256 + c8;
    const bf16x8 v00 = *(const bf16x8*)(base + (size_t)(i0 * 64 + j0) * 256);
    const bf16x8 v01 = *(const bf16x8*)(base + (size_t)(i0 * 64 + j0 + 1) * 256);
    const bf16x8 v10 = *(const bf16x8*)(base + (size_t)((i0 + 1) * 64 + j0) * 256);
    const bf16x8 v11 = *(const bf16x8*)(base + (size_t)((i0 + 1) * 64 + j0 + 1) * 256);
    bf16x8 o;
#pragma unroll
    for (int k = 0; k < 8; ++k) {
        float a00 = bf2f(v00[k]), a01 = bf2f(v01[k]);
        float a10 = bf2f(v10[k]), a11 = bf2f(v11[k]);
        float c0 = a00 + ty * (a10 - a00);
        float c1 = a01 + ty * (a11 - a01);
        o[k] = f2bf(c0 + tx * (c1 - c0));
    }
    *(bf16x8*)(out + ((size_t)b * NP + pos) * 256 + c8) = o;
}

// conv1 weight prep: BN-fold + bf16 + MFMA B-fragment order.
__global__ void k_w1prep(const float* __restrict__ w, const float* __restrict__ bias,
                         const float* __restrict__ g, const float* __restrict__ bb,
                         const float* __restrict__ m, const float* __restrict__ v,
                         short* __restrict__ wb, float* __restrict__ shift) {
    int idx = blockIdx.x * 256 + threadIdx.x;      // < 294912
    int j = idx & 7;
    int lane = (idx >> 3) & 63;
    int nt = (idx >> 9) & 7;
    int tc = idx >> 12;
    int tap = tc % 9, chunk = tc / 9;
    int oc = nt * 16 + (lane & 15);
    int c = chunk * 32 + (lane >> 4) * 8 + j;
    float s = g[oc] * rsqrtf(v[oc] + 1e-5f);
    wb[idx] = f2bf(w[((size_t)oc * 256 + c) * 9 + tap] * s);
    if (idx < 128) {
        float si = g[idx] * rsqrtf(v[idx] + 1e-5f);
        shift[idx] = (bias[idx] - m[idx]) * si + bb[idx];
    }
}

// conv1 as implicit GEMM on MFMA bf16 — 8x8 px tiles + LDS-staged weights.
// Each (chunk,tap) 8KB weight block is fetched from L2 ONCE per block and
// shared by all 4 waves via contiguous lane*16 ds_read_b128 (conflict-free),
// cutting weight L2 traffic 3.6GB -> 0.9GB. Async-STAGE split: global loads
// issued before compute, ds_writes after the read barrier.
__global__ __launch_bounds__(256) void k_conv1mfma(const short* __restrict__ X,
                                                   const bf16x8* __restrict__ WB,
                                                   const float* __restrict__ shift,
                                                   float* __restrict__ out) {
    __shared__ bf16x8 wl[512];          // 8 KB: one (chunk,tap) weight block
    int tid = threadIdx.x;
    int lane = tid & 63, w = tid >> 6;
    int t = blockIdx.x;                 // < 784 = 28x28 tiles of 8x8
    int b = blockIdx.y;
    int ty0 = (t / 28) * 8, tx0 = (t % 28) * 8;
    int l15 = lane & 15, q = lane >> 4;
    int loc = w * 16 + l15;             // wave w owns px loc in [w*16, w*16+16)
    int py0 = ty0 + (loc >> 3), px0 = tx0 + (loc & 7);
    int csub = q * 8;
    f32x4 acc0[8];
#pragma unroll
    for (int nt = 0; nt < 8; ++nt) acc0[nt] = (f32x4){0.f, 0.f, 0.f, 0.f};
    const short* Xb = X + (size_t)b * NP * 256;
    const bf16x8 zv = {0, 0, 0, 0, 0, 0, 0, 0};
    // prologue: stage weights for it=0 and prefetch A for it=0
    bf16x8 na = WB[tid];
    bf16x8 nb = WB[256 + tid];
    wl[tid] = na;
    wl[tid + 256] = nb;
    bf16x8 a_cur = zv;
    {
        int sy = py0 - 1, sx = px0 - 1;     // it=0: chunk0, tap0 (dy=-1,dx=-1)
        if ((unsigned)sy < HW && (unsigned)sx < HW)
            a_cur = *(const bf16x8*)(Xb + ((size_t)sy * HW + sx) * 256 + csub);
    }
    for (int it = 0; it < 72; ++it) {
        __syncthreads();                    // staged weights visible
        bf16x8 a_nxt = zv;
        if (it < 71) {
            na = WB[(it + 1) * 512 + tid];  // issue next weight loads early
            nb = WB[(it + 1) * 512 + 256 + tid];
            int itn = it + 1;
            int cn = itn / 9, tn = itn - cn * 9;
            int sy = py0 + tn / 3 - 1, sx = px0 + (tn % 3) - 1;
            if ((unsigned)sy < HW && (unsigned)sx < HW)
                a_nxt = *(const bf16x8*)(Xb + ((size_t)sy * HW + sx) * 256 + cn * 32 + csub);
        }
#pragma unroll
        for (int nt = 0; nt < 8; ++nt) {
            bf16x8 bf = wl[nt * 64 + lane];
            acc0[nt] = __builtin_amdgcn_mfma_f32_16x16x32_bf16(a_cur, bf, acc0[nt], 0, 0, 0);
        }
        __syncthreads();                    // all reads of wl done
        if (it < 71) {
            wl[tid] = na;
            wl[tid + 256] = nb;
        }
        a_cur = a_nxt;
    }
#pragma unroll
    for (int nt = 0; nt < 8; ++nt) {
        int oc = nt * 16 + l15;
        float sh = shift[oc];
        float* ob = out + ((size_t)(b * 128 + oc)) * NP;
#pragma unroll
        for (int r = 0; r < 4; ++r) {
            int lm = w * 16 + q * 4 + r;
            int py = ty0 + (lm >> 3), px = tx0 + (lm & 7);
            ob[py * HW + px] = fmaxf(acc0[nt][r] + sh, 0.f);
        }
    }
}

// ---- conv3 v3: weight repack (O,C,3,3) -> WP[c][tap][o] ----
__global__ void k_wc3prep(const float* __restrict__ W, float* __restrict__ WP,
                          int C, int O) {
    int idx = blockIdx.x * 256 + threadIdx.x;
    if (idx >= C * 9 * O) return;
    int o = idx % O;
    int t = idx / O;
    int tap = t % 9, c = t / 9;
    WP[idx] = W[((size_t)o * C + c) * 9 + tap];
}

// ---- conv3 v3 main: K-split, all-O-per-block, 32x8 px tile ----
template <int O, int CB>
__global__ __launch_bounds__(256) void k_conv3v3(const float* __restrict__ in,
                                                 const float* __restrict__ WP,
                                                 float* __restrict__ part, int C) {
    __shared__ float sX[8 * 360];               // 8 ch x 10 rows x 36-stride
    int tid = threadIdx.x;
    int tb = blockIdx.x, s = blockIdx.y, b = blockIdx.z;
    int ty0 = (tb / 7) * 8, tx0 = (tb % 7) * 32;
    int px = tid & 31, py = tid >> 5;
    float acc[O];
#pragma unroll
    for (int o = 0; o < O; ++o) acc[o] = 0.f;
    int c0 = s * CB;
    const float* ic = in + ((size_t)b * C + c0) * NP;
    const float* wbase = WP + (size_t)c0 * 9 * O;
    for (int cc = 0; cc < CB; cc += 8) {
        __syncthreads();
        for (int i = tid; i < 8 * 340; i += 256) {
            int c = i / 340;
            int r = i - c * 340;
            int y = r / 34, x = r - y * 34;
            int sy = ty0 + y - 1, sx = tx0 + x - 1;
            float v = 0.f;
            if ((unsigned)sy < HW && (unsigned)sx < HW)
                v = ic[(size_t)(cc + c) * NP + sy * HW + sx];
            sX[c * 360 + y * 36 + x] = v;
        }
        __syncthreads();
        const float* xb = sX + py * 36 + px;
#pragma unroll 1
        for (int c = 0; c < 8; ++c) {
            const float* xc = xb + c * 360;
            const float* wc = wbase + (size_t)(cc + c) * 9 * O;
#pragma unroll
            for (int kh = 0; kh < 3; ++kh)
#pragma unroll
                for (int kw = 0; kw < 3; ++kw) {
                    float xv = xc[kh * 36 + kw];
                    const float* wt = wc + (kh * 3 + kw) * O;
#pragma unroll
                    for (int o = 0; o < O; ++o) acc[o] = fmaf(xv, wt[o], acc[o]);
                }
        }
    }
    int gy = ty0 + py, gx = tx0 + px;
    float* ob = part + ((size_t)(s * BATCH + b) * O) * NP + (size_t)gy * HW + gx;
#pragma unroll
    for (int o = 0; o < O; ++o) ob[(size_t)o * NP] = acc[o];
}

// ---- fused conv2 reduce + bias + sim (prototypes dot) ----
__global__ __launch_bounds__(256) void k_red32sim(const float* __restrict__ part,
                                                  const float* __restrict__ bias,
                                                  const float* __restrict__ proto,
                                                  float* __restrict__ o_pe,
                                                  float* __restrict__ simout) {
    int idx = blockIdx.x * 256 + threadIdx.x;   // < B*NP
    int b = idx / NP, pos = idx - b * NP;
    float v[32];
#pragma unroll
    for (int o = 0; o < 32; ++o) {
        float s = bias[o];
#pragma unroll
        for (int s2 = 0; s2 < 4; ++s2)
            s += part[((size_t)((s2 * BATCH + b) * 32 + o)) * NP + pos];
        v[o] = s;
        o_pe[((size_t)(b * 32 + o)) * NP + pos] = s;
    }
    const float scale = 1.0f / sqrtf(32.0f);
    float* so = simout + (size_t)b * NPROTO * NP + pos;
    for (int q = 0; q < NPROTO; ++q) {
        float acc = 0.f;
#pragma unroll
        for (int e = 0; e < 32; ++e) acc = fmaf(v[e], proto[q * EMBD + e], acc);
        so[(size_t)q * NP] = acc * scale;
    }
}

__global__ void k_init(float* acc) { if (threadIdx.x < 8) acc[threadIdx.x] = 0.f; }

__device__ __forceinline__ float block_reduce_sum(float v) {
    __shared__ float sh[4];
#pragma unroll
    for (int off = 32; off > 0; off >>= 1) v += __shfl_down(v, off);
    int lane = threadIdx.x & 63, wv = threadIdx.x >> 6;
    if (lane == 0) sh[wv] = v;
    __syncthreads();
    return (threadIdx.x == 0) ? (sh[0] + sh[1] + sh[2] + sh[3]) : 0.f;
}

__global__ __launch_bounds__(256) void k_edge(const float* __restrict__ pe,
                                              float* __restrict__ edge,
                                              float* __restrict__ acc) {
    int idx = blockIdx.x * 256 + threadIdx.x;
    int b = idx / NP, pos = idx - b * NP;
    int h = pos / HW, w = pos - h * HW;
    int wn = (w < HW - 1) ? w : HW - 2;
    int hn = (h < HW - 1) ? h : HW - 2;
    const float* pb = pe + (size_t)b * EMBD * NP;
    float sx = 0.f, sy = 0.f;
#pragma unroll 4
    for (int e = 0; e < EMBD; ++e) {
        const float* p = pb + (size_t)e * NP;
        sx += fabsf(p[h * HW + wn] - p[h * HW + wn + 1]);
        sy += fabsf(p[hn * HW + w] - p[hn * HW + HW + w]);
    }
    float ev = (sx + sy) * (0.5f / 32.0f);
    edge[idx] = ev;
    float tot = block_reduce_sum(ev);
    if (threadIdx.x == 0) atomicAdd(acc, tot);
}

// ---- fused 2-pass edge-aware smoothing (LDS-tiled, 16x16 out-tile) ----
__global__ __launch_bounds__(256) void k_smooth2x(const float* __restrict__ sin_,
                                                  const float* __restrict__ edge,
                                                  const float* __restrict__ acc,
                                                  float* __restrict__ sout) {
    __shared__ float sIn[20 * 20];      // origin (oy0-2, ox0-2)
    __shared__ float sE[18 * 18];       // edge at origin (oy0-1, ox0-1)
    __shared__ float s1[18 * 18];       // pass-1 result, origin (oy0-1, ox0-1)
    int tid = threadIdx.x;
    int tile = blockIdx.x, p = blockIdx.y, b = blockIdx.z;
    int oy0 = (tile / 14) * 16, ox0 = (tile % 14) * 16;
    float mean = acc[0] * (1.0f / 100352.0f);
    const float* sc = sin_ + ((size_t)(b * NPROTO + p)) * NP;
    const float* eb = edge + (size_t)b * NP;
    for (int i = tid; i < 400; i += 256) {
        int y = i / 20, x = i - y * 20;
        int gy = oy0 - 2 + y, gx = ox0 - 2 + x;
        float v = 0.f;
        if ((unsigned)gy < HW && (unsigned)gx < HW) v = sc[gy * HW + gx];
        sIn[i] = v;
    }
    for (int i = tid; i < 324; i += 256) {
        int y = i / 18, x = i - y * 18;
        int gy = oy0 - 1 + y, gx = ox0 - 1 + x;
        float e = 0.f;
        if ((unsigned)gy < HW && (unsigned)gx < HW) e = eb[gy * HW + gx];
        sE[i] = e;
    }
    __syncthreads();
    for (int i = tid; i < 324; i += 256) {
        int y = i / 18, x = i - y * 18;
        int gy = oy0 - 1 + y, gx = ox0 - 1 + x;
        float r = 0.f;
        if ((unsigned)gy < HW && (unsigned)gx < HW) {
            const float* c0 = sIn + (y + 1) * 20 + (x + 1);
            float s = c0[-21] + c0[-20] + c0[-19]
                    + c0[-1]  + c0[0]   + c0[1]
                    + c0[19]  + c0[20]  + c0[21];
            float m = (sE[i] > mean) ? 1.f : 0.f;
            r = m * c0[0] + (1.f - m) * (s * (1.0f / 9.0f));
        }
        s1[i] = r;
    }
    __syncthreads();
    {
        int px = tid & 15, py = tid >> 4;
        int gy = oy0 + py, gx = ox0 + px;
        const float* c1 = s1 + (py + 1) * 18 + (px + 1);
        float s = c1[-19] + c1[-18] + c1[-17]
                + c1[-1]  + c1[0]   + c1[1]
                + c1[17]  + c1[18]  + c1[19];
        float m = (sE[(py + 1) * 18 + (px + 1)] > mean) ? 1.f : 0.f;
        sout[((size_t)(b * NPROTO + p)) * NP + (size_t)gy * HW + gx] =
            m * c1[0] + (1.f - m) * (s * (1.0f / 9.0f));
    }
}

__global__ __launch_bounds__(256) void k_entropy(const float* __restrict__ sim,
                                                 float* __restrict__ acc) {
    int idx = blockIdx.x * 256 + threadIdx.x;
    int b = idx / NP, pos = idx - b * NP;
    const float* s = sim + (size_t)b * NPROTO * NP + pos;
    float v[NPROTO];
    float mx = -3.0e38f;
#pragma unroll
    for (int q = 0; q < NPROTO; ++q) { v[q] = s[(size_t)q * NP]; mx = fmaxf(mx, v[q]); }
    float sum = 0.f;
#pragma unroll
    for (int q = 0; q < NPROTO; ++q) { float e = expf(v[q] - mx); v[q] = e; sum += e; }
    float inv = 1.f / sum;
    float ent = 0.f;
#pragma unroll
    for (int q = 0; q < NPROTO; ++q) {
        float a = v[q] * inv;
        ent -= a * logf(a + 1e-8f);
    }
    float tot = block_reduce_sum(ent);
    if (threadIdx.x == 0) atomicAdd(acc + 1, tot);
}

__global__ void k_bb(const float* __restrict__ pb, const float* __restrict__ bs,
                     float* __restrict__ bbuf, float* __restrict__ obb) {
    int t = threadIdx.x;
    if (t < NPROTO) {
        float v = 1.f + tanhf(pb[t]) * bs[0];
        bbuf[t] = v;
        obb[t] = v;
        obb[NPROTO + t] = v;
    }
}

// ---- fused smooth-conv reduce + bias + softmax + act + bgain ----
__global__ __launch_bounds__(256) void k_actsm2(const float* __restrict__ part,
                                                const float* __restrict__ bias,
                                                const float* __restrict__ bb,
                                                float* __restrict__ act,
                                                float* __restrict__ bgain) {
    int idx = blockIdx.x * 256 + threadIdx.x;
    int b = idx / NP, pos = idx - b * NP;
    float v[NPROTO];
    float mx = -3.0e38f;
#pragma unroll
    for (int q = 0; q < NPROTO; ++q) {
        float s = bias[q];
        s += part[((size_t)((0 * BATCH + b) * NPROTO + q)) * NP + pos];
        s += part[((size_t)((1 * BATCH + b) * NPROTO + q)) * NP + pos];
        v[q] = s;
        mx = fmaxf(mx, s);
    }
    float sum = 0.f;
#pragma unroll
    for (int q = 0; q < NPROTO; ++q) { float e = expf(v[q] - mx); v[q] = e; sum += e; }
    float inv = 1.f / sum;
    float* a = act + (size_t)b * NPROTO * NP + pos;
    float bg = 0.f;
#pragma unroll
    for (int q = 0; q < NPROTO; ++q) {
        float p = v[q] * inv;
        a[(size_t)q * NP] = p;
        bg = fmaf(p, bb[q], bg);
    }
    bgain[idx] = bg;
}

__global__ void k_headprep(const float* __restrict__ w1, const float* __restrict__ b1,
                           const float* __restrict__ g1, const float* __restrict__ be1,
                           const float* __restrict__ m1, const float* __restrict__ v1,
                           const float* __restrict__ w2, const float* __restrict__ b2,
                           const float* __restrict__ g2, const float* __restrict__ be2,
                           const float* __restrict__ m2, const float* __restrict__ v2,
                           float* __restrict__ wf) {
    int oc = blockIdx.x * 256 + threadIdx.x;
    if (oc >= 512) return;
    float s1 = g1[oc] * rsqrtf(v1[oc] + 1e-5f);
#pragma unroll
    for (int k = 0; k < 9; ++k) wf[oc * 9 + k] = w1[oc * 9 + k] * s1;
    wf[41472 + oc] = (b1[oc] - m1[oc]) * s1 + be1[oc];
    float s2 = g2[oc] * rsqrtf(v2[oc] + 1e-5f);
    int g = oc >> 3, j = oc & 7;
#pragma unroll
    for (int icc = 0; icc < 8; ++icc)
#pragma unroll
        for (int k = 0; k < 9; ++k)
            wf[4608 + (size_t)g * 576 + icc * 72 + j * 9 + k] = w2[((size_t)oc * 8 + icc) * 9 + k] * s2;
    wf[41984 + oc] = (b2[oc] - m2[oc]) * s2 + be2[oc];
}

// fused 3-layer grouped heads, 16x16 out-tile (R4 verified version).
__global__ __launch_bounds__(256) void k_heads(
    const float* __restrict__ act, const float* __restrict__ wf,
    const float* __restrict__ w3, const float* __restrict__ b3,
    float* __restrict__ res) {
    __shared__ float sA[22 * 24];           // origin (oy0-3, ox0-3), stride 24
    __shared__ float sH1[8][20 * 22];       // origin (oy0-2, ox0-2), stride 22
    __shared__ float sH2[8][18 * 18];       // origin (oy0-1, ox0-1), stride 18
    int tid = threadIdx.x;
    int tile = blockIdx.x, g = blockIdx.y, b = blockIdx.z;
    int oy0 = (tile / 14) * 16, ox0 = (tile % 14) * 16;
    const float* ain = act + (size_t)(b * NPROTO + g) * NP;

    for (int i = tid; i < 484; i += 256) {
        int y = i / 22, x = i - y * 22;
        int gy = oy0 - 3 + y, gx = ox0 - 3 + x;
        float v = 0.f;
        if ((unsigned)gy < HW && (unsigned)gx < HW) v = ain[gy * HW + gx];
        sA[y * 24 + x] = v;
    }
    __syncthreads();

    // stage1: 20x20, 1 px/thread
    const float* b1f = wf + 41472 + g * 8;
    for (int i = tid; i < 400; i += 256) {
        int y = i / 20, x = i - y * 20;
        int gy = oy0 - 2 + y, gx = ox0 - 2 + x;
        float keep = ((unsigned)gy < HW && (unsigned)gx < HW) ? 1.f : 0.f;
        const float* s0 = sA + y * 24 + x;
        float r0 = s0[0],  r1 = s0[1],  r2 = s0[2];
        float r3 = s0[24], r4 = s0[25], r5 = s0[26];
        float r6 = s0[48], r7 = s0[49], r8 = s0[50];
#pragma unroll
        for (int j = 0; j < 8; ++j) {
            const float* w = wf + (g * 8 + j) * 9;
            float v = fmaf(r0, w[0], fmaf(r1, w[1], fmaf(r2, w[2],
                      fmaf(r3, w[3], fmaf(r4, w[4], fmaf(r5, w[5],
                      fmaf(r6, w[6], fmaf(r7, w[7], fmaf(r8, w[8], b1f[j])))))))));
            sH1[j][y * 22 + x] = fmaxf(v, 0.f) * keep;
        }
    }
    __syncthreads();

    // stage2: 18x18 as 18x9 pixel pairs, f32x2 packed
    const float* w2f = wf + 4608 + (size_t)g * 576;
    const float* b2f = wf + 41984 + g * 8;
    if (tid < 162) {
        int y2 = tid / 9, xp = (tid - y2 * 9) * 2;
        f32x2 a2[8];
#pragma unroll
        for (int j = 0; j < 8; ++j) { float bv = b2f[j]; a2[j] = (f32x2){bv, bv}; }
#pragma unroll
        for (int icc = 0; icc < 8; ++icc) {
            const float* s0 = &sH1[icc][y2 * 22 + xp];
            f32x2 t[9];
#pragma unroll
            for (int r = 0; r < 3; ++r) {
                float f0 = s0[r * 22], f1 = s0[r * 22 + 1];
                float f2 = s0[r * 22 + 2], f3 = s0[r * 22 + 3];
                t[r * 3 + 0] = (f32x2){f0, f1};
                t[r * 3 + 1] = (f32x2){f1, f2};
                t[r * 3 + 2] = (f32x2){f2, f3};
            }
            const float* wr = w2f + icc * 72;
#pragma unroll
            for (int j = 0; j < 8; ++j) {
                const float* wj = wr + j * 9;
#pragma unroll
                for (int k = 0; k < 9; ++k) {
                    float wv = wj[k];
                    a2[j] = __builtin_elementwise_fma(t[k], (f32x2){wv, wv}, a2[j]);
                }
            }
        }
        int gy = oy0 - 1 + y2;
        int gx0 = ox0 - 1 + xp;
        float k0 = ((unsigned)gy < HW && (unsigned)gx0 < HW) ? 1.f : 0.f;
        float k1 = ((unsigned)gy < HW && (unsigned)(gx0 + 1) < HW) ? 1.f : 0.f;
        f32x2 kp = (f32x2){k0, k1};
        const f32x2 z2 = (f32x2){0.f, 0.f};
#pragma unroll
        for (int j = 0; j < 8; ++j) {
            f32x2 v = __builtin_elementwise_max(a2[j], z2) * kp;
            sH2[j][y2 * 18 + xp] = v.x;
            sH2[j][y2 * 18 + xp + 1] = v.y;
        }
    }
    __syncthreads();

    // stage3: 16x16 as 16x8 pairs, f32x2 packed
    if (tid < 128) {
        int y3 = tid >> 3, xp = (tid & 7) * 2;
        float bv = b3[g];
        f32x2 a2 = (f32x2){bv, bv};
#pragma unroll
        for (int icc = 0; icc < 8; ++icc) {
            const float* s0 = &sH2[icc][y3 * 18 + xp];
            const float* w = w3 + (size_t)(g * 8 + icc) * 9;
#pragma unroll
            for (int r = 0; r < 3; ++r) {
                float f0 = s0[r * 18], f1 = s0[r * 18 + 1];
                float f2 = s0[r * 18 + 2], f3 = s0[r * 18 + 3];
                float w0 = w[r * 3], w1 = w[r * 3 + 1], w2v = w[r * 3 + 2];
                a2 = __builtin_elementwise_fma((f32x2){f0, f1}, (f32x2){w0, w0}, a2);
                a2 = __builtin_elementwise_fma((f32x2){f1, f2}, (f32x2){w1, w1}, a2);
                a2 = __builtin_elementwise_fma((f32x2){f2, f3}, (f32x2){w2v, w2v}, a2);
            }
        }
        float* rp = res + (size_t)(b * NPROTO + g) * NP + (size_t)(oy0 + y3) * HW + (ox0 + xp);
        rp[0] = a2.x;
        rp[1] = a2.y;
    }
}

__global__ __launch_bounds__(256) void k_final(const float* __restrict__ act,
                                               const float* __restrict__ res,
                                               const float* __restrict__ bgain,
                                               const float* __restrict__ rscale,
                                               float* __restrict__ owt,
                                               float* __restrict__ oibm) {
    int idx = blockIdx.x * 256 + threadIdx.x;
    int b = idx / NP, pos = idx - b * NP;
    const float* a = act + (size_t)b * NPROTO * NP + pos;
    const float* r = res + (size_t)b * NPROTO * NP + pos;
    float wt = 0.f;
#pragma unroll
    for (int q = 0; q < NPROTO; ++q) wt = fmaf(a[(size_t)q * NP], r[(size_t)q * NP], wt);
    owt[idx] = wt;
    float gn = bgain[idx] * (1.f + tanhf(wt) * rscale[0]);
    gn = fminf(fmaxf(gn, 0.5f), 2.0f);
    oibm[idx] = gn;
}

__global__ void k_entfinal(const float* __restrict__ acc, float* __restrict__ o) {
    if (threadIdx.x == 0) o[0] = acc[1] * (1.0f / 100352.0f);
}

// ======================================================================
extern "C" void kernel_launch(void* const* d_in, const int* in_sizes, int n_in,
                              void* d_out, int out_size, void* d_ws, size_t ws_size,
                              hipStream_t stream) {
    const float* tokens[4] = {(const float*)d_in[0], (const float*)d_in[1],
                              (const float*)d_in[2], (const float*)d_in[3]};
    const float* proj_w[4] = {(const float*)d_in[4], (const float*)d_in[6],
                              (const float*)d_in[8], (const float*)d_in[10]};
    const float* proj_b[4] = {(const float*)d_in[5], (const float*)d_in[7],
                              (const float*)d_in[9], (const float*)d_in[11]};
    const float* up_w0 = (const float*)d_in[12]; const float* up_b0 = (const float*)d_in[13];
    const float* up_w1 = (const float*)d_in[14]; const float* up_b1 = (const float*)d_in[15];
    const float* down_w3 = (const float*)d_in[16]; const float* down_b3 = (const float*)d_in[17];
    const float* fuse_w = (const float*)d_in[18]; const float* fuse_b = (const float*)d_in[19];
    const float* pe_w1 = (const float*)d_in[20]; const float* pe_b1 = (const float*)d_in[21];
    const float* pe_bn_g = (const float*)d_in[22]; const float* pe_bn_b = (const float*)d_in[23];
    const float* pe_bn_m = (const float*)d_in[24]; const float* pe_bn_v = (const float*)d_in[25];
    const float* pe_w2 = (const float*)d_in[26]; const float* pe_b2 = (const float*)d_in[27];
    const float* prototypes = (const float*)d_in[28];
    const float* proto_biases = (const float*)d_in[29];
    const float* bias_scale = (const float*)d_in[30];
    const float* smooth_w = (const float*)d_in[31]; const float* smooth_b = (const float*)d_in[32];
    const float* hw1 = (const float*)d_in[33]; const float* hb1 = (const float*)d_in[34];
    const float* hg1 = (const float*)d_in[35]; const float* hbe1 = (const float*)d_in[36];
    const float* hm1 = (const float*)d_in[37]; const float* hv1 = (const float*)d_in[38];
    const float* hw2 = (const float*)d_in[39]; const float* hb2 = (const float*)d_in[40];
    const float* hg2 = (const float*)d_in[41]; const float* hbe2 = (const float*)d_in[42];
    const float* hm2 = (const float*)d_in[43]; const float* hv2 = (const float*)d_in[44];
    const float* hw3 = (const float*)d_in[45]; const float* hb3 = (const float*)d_in[46];
    const float* rscale = (const float*)d_in[47];
    (void)in_sizes; (void)n_in; (void)out_size; (void)ws_size;

    float* ws = (float*)d_ws;
    float* FEATS[4] = {ws + OFF_FEATS0, ws + OFF_FEATS1, ws + OFF_FEATS2, ws + OFF_FEATS3};
    float* TOKT = ws + OFF_TOKT;
    float* F0 = ws + OFF_F0; float* F1 = ws + OFF_F1; float* F3 = ws + OFF_F3;
    short* FUSEDBF = (short*)(ws + OFF_FUSEDBF);
    short* P64C = (short*)(ws + OFF_P64C);
    short* P224C = (short*)(ws + OFF_P224C);
    short* WB = (short*)(ws + OFF_WB);
    short* WFUSE = (short*)(ws + OFF_WFUSE);
    float* SHIFT = ws + OFF_SHIFT;
    float* T1 = ws + OFF_T1;
    float* SIMA = ws + OFF_SIMA;
    float* SIMRAW = ws + OFF_SIMRAW;
    float* EDGE = ws + OFF_EDGE; float* RES = ws + OFF_RES;
    float* BGAIN = ws + OFF_BGAIN; float* BBUF = ws + OFF_BB; float* ACC = ws + OFF_ACC;
    float* WF = ws + OFF_WF;
    float* WDP = ws + OFF_WD;
    float* PART = ws + OFF_PART;
    float* WCV0 = ws + OFF_WCV0;
    float* WCV1 = ws + OFF_WCV1;
    float* WC2 = ws + OFF_WC2;
    float* WSM = ws + OFF_WSM;
    float* PC2 = ws + OFF_PC2;      // conv2 partials (dead-P224C window)
    float* PSM = ws + OFF_PSM;      // smooth partials (dead-T1/SIMRAW window)

    float* out = (float*)d_out;
    float* o_ibm = out + O_IBM; float* o_act = out + O_ACT; float* o_bb = out + O_BB;
    float* o_wt = out + O_WT; float* o_pe = out + O_PE; float* o_ent = out + O_ENT;

    const int OCH[4] = {256, 512, 1024, 1024};
    for (int s = 0; s < 4; ++s)
        k_transpose<<<768, 256, 0, stream>>>(tokens[s], TOKT + s * 196608);
    for (int s = 0; s < 4; ++s)
        k_proj<<<dim3(OCH[s], BATCH), 256, 0, stream>>>(TOKT + s * 196608, proj_w[s], proj_b[s],
                                                        FEATS[s], OCH[s]);
    // convT v2: pack W (C x M tiled transpose), then LDS-GEMM
    k_wcvprep<16><<<dim3(8, 128), 256, 0, stream>>>(up_w0, WCV0, 256, 4096);
    k_wcvprep<8><<<dim3(16, 64), 256, 0, stream>>>(up_w1, WCV1, 512, 2048);
    k_convt2<16, 64, 4><<<dim3(256, BATCH), 256, 0, stream>>>(FEATS[0], WCV0, up_b0, F0, 256, 256);
    k_convt2<8, 64, 2><<<dim3(256, BATCH), 256, 0, stream>>>(FEATS[1], WCV1, up_b1, F1, 512, 512);
    // down-conv v2: pack W, K-split GEMM, reduce (+bias)
    k_wdprep<<<dim3(288, 32), 256, 0, stream>>>(down_w3, WDP);
    k_down2<<<dim3(16, 16, BATCH), 256, 0, stream>>>(FEATS[3], WDP, PART);
    k_downred<<<512, 256, 0, stream>>>(PART, down_b3, F3);
    // conv3 v3 weight packs (early, independent)
    k_wc3prep<<<144, 256, 0, stream>>>(pe_w2, WC2, 128, 32);
    k_wc3prep<<<144, 256, 0, stream>>>(smooth_w, WSM, 64, 64);
    k_wfuseprep<<<2816, 256, 0, stream>>>(fuse_w, WFUSE);
    k_fusedcat_bf<<<90112, 256, 0, stream>>>(F0, F1, FEATS[2], F3, FUSEDBF);
    k_fuse_mfma<<<512, 256, 0, stream>>>(FUSEDBF, (const bf16x8*)WFUSE, fuse_b, P64C);
    // FUSEDBF dead: WB/SHIFT (inside its range) safe now
    k_w1prep<<<1152, 256, 0, stream>>>(pe_w1, pe_b1, pe_bn_g, pe_bn_b, pe_bn_m, pe_bn_v,
                                       WB, SHIFT);
    k_resize224bf2<<<12544, 256, 0, stream>>>(P64C, P224C);
    // conv1: 8x8 px tiles + LDS weight staging (L2 weight traffic fix)
    k_conv1mfma<<<dim3(784, BATCH), 256, 0, stream>>>(P224C, (const bf16x8*)WB, SHIFT, T1);
    // conv2: K-split 4 (P224C dead -> PC2 window free)
    k_conv3v3<32, 32><<<dim3(196, 4, BATCH), 256, 0, stream>>>(T1, WC2, PC2, 128);
    // fused reduce+sim: raw sim -> SIMRAW (dead-T1 window; T1 consumed above)
    k_red32sim<<<392, 256, 0, stream>>>(PC2, pe_b2, prototypes, o_pe, SIMRAW);
    k_init<<<1, 64, 0, stream>>>(ACC);
    k_edge<<<392, 256, 0, stream>>>(o_pe, EDGE, ACC);
    // fused 2-pass smoothing: SIMRAW -> SIMA (PC2 dead; disjoint buffers, no race)
    k_smooth2x<<<dim3(196, NPROTO, BATCH), 256, 0, stream>>>(SIMRAW, EDGE, ACC, SIMA);
    k_entropy<<<392, 256, 0, stream>>>(SIMA, ACC);
    // smooth conv: K-split 2 (SIMRAW dead -> PSM window free)
    k_conv3v3<64, 32><<<dim3(196, 2, BATCH), 256, 0, stream>>>(SIMA, WSM, PSM, 64);
    k_bb<<<1, 64, 0, stream>>>(proto_biases, bias_scale, BBUF, o_bb);
    // fused reduce+softmax+act+bgain
    k_actsm2<<<392, 256, 0, stream>>>(PSM, smooth_b, BBUF, o_act, BGAIN);
    k_headprep<<<2, 256, 0, stream>>>(hw1, hb1, hg1, hbe1, hm1, hv1,
                                      hw2, hb2, hg2, hbe2, hm2, hv2, WF);
    k_heads<<<dim3(196, 64, BATCH), 256, 0, stream>>>(o_act, WF, hw3, hb3, RES);
    k_final<<<392, 256, 0, stream>>>(o_act, RES, BGAIN, rscale, o_wt, o_ibm);
    k_entfinal<<<1, 1, 0, stream>>>(ACC, o_ent);
}